// Round 5
// baseline (1136.008 us; speedup 1.0000x reference)
//
#include <hip/hip_runtime.h>
#include <math.h>

// TriDirectionalMamba: C=64, N=16, DI=128, K=4, DT_RANK=4, L=48, 48^3, B=1.
// v5 pipeline per dir:
//   K1: LN + in_proj (xin half only) -> tb[p][128] in OUTPUT-token order
//       (streaming writes, no tau math).
//   K2: per-seq conv+silu -> x_proj -> scan, tb gather/scatter via base+t*TS,
//       IN-PLACE (y overwrites xin). 31.5KB LDS -> 5 blocks/CU.
//   K3: streaming z read + res RECOMPUTED (x reload + LN + GEMM) + gate +
//       out_proj + LDS transpose -> coalesced RMW of out.
// tb = 56.6 MB workspace. Fallback monolithic v1 if ws too small.

#define CS   110592                        // channel stride in x
#define TBF  (110592 * 128)                // tb floats
#define IPT_OFF  TBF
#define OPT_OFF  (IPT_OFF + 3 * 64 * 256)
#define WS_FLOATS (OPT_OFF + 3 * 128 * 64)

__device__ __forceinline__ float fast_silu(float x) {
    return x / (1.0f + __expf(-x));
}
// branchless stable softplus: max(x,0) + log(1+exp(-|x|))
__device__ __forceinline__ float softplus_f(float x) {
    float em = __expf(-fabsf(x));
    return fmaxf(x, 0.f) + __logf(1.f + em);
}

// ---------------------------------------------------------------- prep ----
__global__ void prep_kernel(const float* __restrict__ ip,
                            const float* __restrict__ op,
                            float* __restrict__ ws)
{
    float* ipT = ws + IPT_OFF;   // [dir][c][256]  (j = out channel 0..255)
    float* opT = ws + OPT_OFF;   // [dir][dch][64]
    int i = blockIdx.x * 256 + threadIdx.x;
    if (i < 3 * 256 * 64) {
        int dir = i / 16384, r = i % 16384, j = r / 64, c = r % 64;
        ipT[dir * 16384 + c * 256 + j] = ip[i];
    } else {
        int k = i - 3 * 256 * 64;
        if (k < 3 * 64 * 128) {
            int dir = k / 8192, r = k % 8192, c = r / 128, dch = r % 128;
            opT[dir * 8192 + dch * 64 + c] = op[k];
        }
    }
}

// ----------------------------------------------------------------- K1 -----
// Block = 64 consecutive OUTPUT tokens, 256 threads. X staged c-major in LDS;
// LN by wave 0; GEMM thread = (token-half, xin channel). Streaming stores:
// tb[p][ch], p contiguous -> 32KB contiguous per block.
template<int DIR>
__global__ __launch_bounds__(256, 4)
void k1_lnproj(const float* __restrict__ x,
               const float* __restrict__ ln_g,
               const float* __restrict__ ln_b,
               float* __restrict__ ws)
{
    __shared__ float Xs[64 * 64];    // [c][tok]
    const float* ipT = ws + IPT_OFF + DIR * 16384;
    float* tb = ws;
    const int tid = threadIdx.x;
    const int p0 = blockIdx.x * 64;

    {
        const int c0 = tid >> 6, j = tid & 63;
#pragma unroll
        for (int cc = 0; cc < 16; cc++) {
            int c = cc * 4 + c0;
            Xs[c * 64 + j] = x[c * CS + p0 + j];
        }
    }
    __syncthreads();

    if (tid < 64) {
        float s1 = 0.f, s2 = 0.f;
#pragma unroll
        for (int c = 0; c < 64; c++) {
            float v = Xs[c * 64 + tid];
            s1 += v; s2 += v * v;
        }
        float m  = s1 * (1.f / 64.f);
        float rs = rsqrtf(s2 * (1.f / 64.f) - m * m + 1e-5f);
#pragma unroll
        for (int c = 0; c < 64; c++) {
            Xs[c * 64 + tid] = (Xs[c * 64 + tid] - m) * rs * ln_g[DIR * 64 + c]
                               + ln_b[DIR * 64 + c];
        }
    }
    __syncthreads();

    const int ch = tid & 127, half = tid >> 7;
    float wgt[64];
#pragma unroll
    for (int c = 0; c < 64; c++) wgt[c] = ipT[c * 256 + ch];

#pragma unroll
    for (int gg = 0; gg < 2; gg++) {
        int g = half * 2 + gg;
        float acc[16];
#pragma unroll
        for (int i = 0; i < 16; i++) acc[i] = 0.f;
#pragma unroll 8
        for (int c = 0; c < 64; c++) {
            const float4* xr = (const float4*)&Xs[c * 64 + g * 16];
            float4 x0 = xr[0], x1 = xr[1], x2 = xr[2], x3 = xr[3];
            float wv = wgt[c];
            acc[0]  += x0.x * wv; acc[1]  += x0.y * wv;
            acc[2]  += x0.z * wv; acc[3]  += x0.w * wv;
            acc[4]  += x1.x * wv; acc[5]  += x1.y * wv;
            acc[6]  += x1.z * wv; acc[7]  += x1.w * wv;
            acc[8]  += x2.x * wv; acc[9]  += x2.y * wv;
            acc[10] += x2.z * wv; acc[11] += x2.w * wv;
            acc[12] += x3.x * wv; acc[13] += x3.y * wv;
            acc[14] += x3.z * wv; acc[15] += x3.w * wv;
        }
#pragma unroll
        for (int i = 0; i < 16; i++)
            tb[(size_t)(p0 + g * 16 + i) * 128 + ch] = acc[i];
    }
}

// ----------------------------------------------------------------- K2 -----
// One block = one sequence (128 thr). tb accessed at (base + t*TS) rows,
// in-place (reads xin, writes y+u*D ungated). LDS 31.5KB -> 5 blocks/CU.
template<int DIR>
__global__ __launch_bounds__(128, 2)
void k2_scan(const float* __restrict__ conv_w,
             const float* __restrict__ conv_b,
             const float* __restrict__ x_proj,
             const float* __restrict__ dt_w,
             const float* __restrict__ dt_b,
             const float* __restrict__ A_log,
             const float* __restrict__ D_ssm,
             float* __restrict__ ws)
{
    __shared__ float u_s[48 * 128];   // XOR-swizzled float4 groups per row
    __shared__ float xd_s[48 * 36];   // rows 144B aligned; dlt|B|C
    float* tb = ws;
    const int tid = threadIdx.x;
    const int s = blockIdx.x;

    int base, TS;
    if (DIR == 0)      { base = s;                               TS = 2304; }
    else if (DIR == 1) { base = (s / 48) * 2304 + (s % 48);      TS = 48;   }
    else               { base = (s / 48) * 2304 + (s % 48) * 48; TS = 1;    }

    // --- phase A: depthwise causal conv + silu (thread = d) ---
    {
        const int d = tid;
        float xin[48];
#pragma unroll
        for (int t = 0; t < 48; t++)
            xin[t] = tb[(size_t)(base + t * TS) * 128 + d];
        float4 cw = *(const float4*)(conv_w + DIR * 512 + d * 4);
        float cb  = conv_b[DIR * 128 + d];
#pragma unroll
        for (int t = 0; t < 48; t++) {
            float a0 = (t >= 3) ? xin[t-3] : 0.f;
            float a1 = (t >= 2) ? xin[t-2] : 0.f;
            float a2 = (t >= 1) ? xin[t-1] : 0.f;
            float v = cw.x * a0 + cw.y * a1 + cw.z * a2 + cw.w * xin[t] + cb;
            // swizzled store: float4-group (d>>2) -> (d>>2)^(t&7)
            u_s[t * 128 + (((((d >> 2) ^ (t & 7))) << 2) | (d & 3))] = fast_silu(v);
        }
    }
    __syncthreads();

    // --- phase B: x_proj u(128)->x_dbl(36); lane=t, j split by wave ---
    {
        const int t  = tid & 63;
        const int wv = __builtin_amdgcn_readfirstlane(tid >> 6);
        const int tr = (t < 48) ? t : 47;       // clamp: keep loads uniform
        const int sw = tr & 7;
        float acc[18];
#pragma unroll
        for (int j = 0; j < 18; j++) acc[j] = 0.f;
        const float* xpw = x_proj + DIR * 36 * 128 + (wv * 18) * 128;
        const float4* urow = (const float4*)&u_s[tr * 128];
#pragma unroll
        for (int qc = 0; qc < 4; qc++) {
            float4 u4[8];
#pragma unroll
            for (int q = 0; q < 8; q++) u4[q] = urow[qc * 8 + (q ^ sw)];
#pragma unroll
            for (int j = 0; j < 18; j++) {
                const float4* wr = (const float4*)(xpw + j * 128 + qc * 32);
                float a0 = 0.f, a1 = 0.f, a2 = 0.f, a3 = 0.f;
#pragma unroll
                for (int q = 0; q < 8; q++) {
                    float4 w4 = wr[q];
                    a0 += u4[q].x * w4.x; a1 += u4[q].y * w4.y;
                    a2 += u4[q].z * w4.z; a3 += u4[q].w * w4.w;
                }
                acc[j] += (a0 + a1) + (a2 + a3);
            }
        }
        if (t < 48) {
#pragma unroll
            for (int j = 0; j < 18; j++) xd_s[t * 36 + wv * 18 + j] = acc[j];
        }
    }
    __syncthreads();

    // --- phase C: selective scan (thread = d), 16 parallel v_exp per step ---
    {
        const int d = tid;
        float A[16];
        {
            const float4* al = (const float4*)(A_log + DIR * 2048 + d * 16);
#pragma unroll
            for (int q = 0; q < 4; q++) {
                float4 v = al[q];
                A[4*q+0] = -__expf(v.x); A[4*q+1] = -__expf(v.y);
                A[4*q+2] = -__expf(v.z); A[4*q+3] = -__expf(v.w);
            }
        }
        float4 dtw = *(const float4*)(dt_w + DIR * 512 + d * 4);
        float dtbv = dt_b[DIR * 128 + d];
        float dsv  = D_ssm[DIR * 128 + d];
        float h[16];
#pragma unroll
        for (int n = 0; n < 16; n++) h[n] = 0.f;

        const int dsw_hi = d >> 2, dlo = d & 3;
        for (int tt = 0; tt < 48; tt++) {
            const float4* xr4 = (const float4*)&xd_s[tt * 36];
            float4 R0 = xr4[0];
            float uu = u_s[tt * 128 + (((dsw_hi ^ (tt & 7)) << 2) | dlo)];
            float dl = dtbv + dtw.x*R0.x + dtw.y*R0.y + dtw.z*R0.z + dtw.w*R0.w;
            float delta = softplus_f(dl);
            float du = delta * uu;
            float4 B0 = xr4[1], B1 = xr4[2], B2 = xr4[3], B3 = xr4[4];
            float4 C0 = xr4[5], C1 = xr4[6], C2 = xr4[7], C3 = xr4[8];
            float y0 = 0.f, y1 = 0.f, y2 = 0.f, y3 = 0.f;
#define HN(n, Bc, Cc, ya) { float e = __expf(delta * A[n]); \
            h[n] = e * h[n] + du * (Bc); ya += h[n] * (Cc); }
            HN(0,  B0.x, C0.x, y0) HN(1,  B0.y, C0.y, y1)
            HN(2,  B0.z, C0.z, y2) HN(3,  B0.w, C0.w, y3)
            HN(4,  B1.x, C1.x, y0) HN(5,  B1.y, C1.y, y1)
            HN(6,  B1.z, C1.z, y2) HN(7,  B1.w, C1.w, y3)
            HN(8,  B2.x, C2.x, y0) HN(9,  B2.y, C2.y, y1)
            HN(10, B2.z, C2.z, y2) HN(11, B2.w, C2.w, y3)
            HN(12, B3.x, C3.x, y0) HN(13, B3.y, C3.y, y1)
            HN(14, B3.z, C3.z, y2) HN(15, B3.w, C3.w, y3)
#undef HN
            tb[(size_t)(base + tt * TS) * 128 + d] =
                ((y0 + y1) + (y2 + y3)) + uu * dsv;
        }
    }
}

// ----------------------------------------------------------------- K3 -----
// One block = 48 consecutive output tokens (d_sp,h). Streaming z read,
// res recomputed (x reload + LN + GEMM), gate, out_proj, transpose, RMW out.
template<int DIR, bool FIRST>
__global__ __launch_bounds__(128, 4)
void k3_outproj(const float* __restrict__ x,
                const float* __restrict__ ln_g,
                const float* __restrict__ ln_b,
                const float* __restrict__ alpha,
                float* __restrict__ ws,
                float* __restrict__ out)
{
    __shared__ float sb[48 * 132];   // z-gated [48][132]; reused outT[64][49]
    __shared__ float xs[64 * 52];    // x tile [c][w], pad 52
    float* tb = ws;
    const float* ipT = ws + IPT_OFF + DIR * 16384;
    const float* opT = ws + OPT_OFF + DIR * 8192;
    const int tid = threadIdx.x;
    const int b = blockIdx.x;
    const int d_sp = b / 48;
    const int h = b - d_sp * 48;
    const int obase = d_sp * 2304 + h * 48;

    float a0 = alpha[0], a1 = alpha[1], a2 = alpha[2];
    float mx = fmaxf(a0, fmaxf(a1, a2));
    float e0 = __expf(a0 - mx), e1 = __expf(a1 - mx), e2 = __expf(a2 - mx);
    float wdir = ((DIR == 0) ? e0 : (DIR == 1) ? e1 : e2) / (e0 + e1 + e2);

    // stage x tile (coalesced 192B runs)
    for (int o = tid; o < 64 * 48; o += 128) {
        int c = o / 48, w = o - c * 48;
        xs[c * 52 + w] = x[c * CS + obase + w];
    }
    __syncthreads();

    // LN per token (threads 0..47)
    if (tid < 48) {
        const int w = tid;
        float s1 = 0.f, s2 = 0.f;
#pragma unroll
        for (int c = 0; c < 64; c++) {
            float v = xs[c * 52 + w];
            s1 += v; s2 += v * v;
        }
        float m  = s1 * (1.f / 64.f);
        float rs = rsqrtf(s2 * (1.f / 64.f) - m * m + 1e-5f);
#pragma unroll
        for (int c = 0; c < 64; c++) {
            xs[c * 52 + w] = (xs[c * 52 + w] - m) * rs * ln_g[DIR * 64 + c]
                             + ln_b[DIR * 64 + c];
        }
    }
    __syncthreads();

    // res GEMM + gate with streamed z (thread = d)
    {
        const int d = tid;
        float wgt2[64];
#pragma unroll
        for (int c = 0; c < 64; c++) wgt2[c] = ipT[c * 256 + 128 + d];
#pragma unroll
        for (int wb = 0; wb < 4; wb++) {
            float acc[12];
#pragma unroll
            for (int i = 0; i < 12; i++) acc[i] = 0.f;
#pragma unroll 8
            for (int c = 0; c < 64; c++) {
                const float4* xr = (const float4*)&xs[c * 52 + wb * 12];
                float4 v0 = xr[0], v1 = xr[1], v2 = xr[2];
                float wv = wgt2[c];
                acc[0] += v0.x * wv; acc[1] += v0.y * wv;
                acc[2] += v0.z * wv; acc[3] += v0.w * wv;
                acc[4] += v1.x * wv; acc[5] += v1.y * wv;
                acc[6] += v1.z * wv; acc[7] += v1.w * wv;
                acc[8] += v2.x * wv; acc[9] += v2.y * wv;
                acc[10] += v2.z * wv; acc[11] += v2.w * wv;
            }
#pragma unroll
            for (int i = 0; i < 12; i++) {
                int w = wb * 12 + i;
                float zv = tb[(size_t)(obase + w) * 128 + d];
                sb[w * 132 + d] = zv * fast_silu(acc[i]);
            }
        }
    }
    __syncthreads();

    // out_proj (thread = (wg, cp)): 64 out-ch split 2x32, 12 tokens per wg
    const int cp = tid & 31;
    const int wg = tid >> 5;
    float acc0[12], acc1[12];
#pragma unroll
    for (int i = 0; i < 12; i++) { acc0[i] = 0.f; acc1[i] = 0.f; }
#pragma unroll 2
    for (int dc = 0; dc < 32; dc++) {
        float w0[4], w1[4];
#pragma unroll
        for (int i = 0; i < 4; i++) {
            w0[i] = opT[(dc * 4 + i) * 64 + cp];
            w1[i] = opT[(dc * 4 + i) * 64 + cp + 32];
        }
#pragma unroll
        for (int i = 0; i < 12; i++) {
            int w = wg * 12 + i;
            float4 z4 = *(const float4*)&sb[w * 132 + dc * 4];
            acc0[i] += z4.x * w0[0] + z4.y * w0[1] + z4.z * w0[2] + z4.w * w0[3];
            acc1[i] += z4.x * w1[0] + z4.y * w1[1] + z4.z * w1[2] + z4.w * w1[3];
        }
    }
    __syncthreads();
#pragma unroll
    for (int i = 0; i < 12; i++) {
        int w = wg * 12 + i;
        sb[cp * 49 + w]        = acc0[i];
        sb[(cp + 32) * 49 + w] = acc1[i];
    }
    __syncthreads();
    for (int o = tid; o < 3072; o += 128) {
        int c = o / 48, w = o - c * 48;
        int addr = c * CS + obase + w;
        float val = wdir * sb[c * 49 + w];
        if (!FIRST) val += out[addr];
        out[addr] = val;
    }
}

// =================== fallback v1 (round-1, known-good) =====================
template<int DIR, bool FIRST>
__global__ __launch_bounds__(128, 2)
void mamba_dir_v1(const float* __restrict__ x, const float* __restrict__ in_proj,
                  const float* __restrict__ conv_w, const float* __restrict__ conv_b,
                  const float* __restrict__ x_proj, const float* __restrict__ dt_w,
                  const float* __restrict__ dt_b, const float* __restrict__ A_log,
                  const float* __restrict__ D_ssm, const float* __restrict__ out_proj,
                  const float* __restrict__ ln_g, const float* __restrict__ ln_b,
                  const float* __restrict__ alpha, float* __restrict__ out)
{
    __shared__ float xs_s[48 * 68];
    __shared__ float u_s[48 * 128];
    __shared__ float xd_s[48 * 40];
    const int tid = threadIdx.x;
    const int lane = tid & 63;
    const int wv = __builtin_amdgcn_readfirstlane(tid >> 6);
    const int s = blockIdx.x;
    int base, TS;
    if (DIR == 0)      { base = s;                               TS = 2304; }
    else if (DIR == 1) { base = (s / 48) * 2304 + (s % 48);      TS = 48;   }
    else               { base = (s / 48) * 2304 + (s % 48) * 48; TS = 1;    }
    const float* ip = in_proj + DIR * 256 * 64;
    const float* xp = x_proj + DIR * 36 * 128;
    const float* op = out_proj + DIR * 64 * 128;
    float a0 = alpha[0], a1 = alpha[1], a2 = alpha[2];
    float mx = fmaxf(a0, fmaxf(a1, a2));
    float e0 = __expf(a0 - mx), e1 = __expf(a1 - mx), e2 = __expf(a2 - mx);
    float wdir = ((DIR == 0) ? e0 : (DIR == 1) ? e1 : e2) / (e0 + e1 + e2);
    for (int o = tid; o < 48 * 64; o += 128) {
        int t = o % 48, c = o / 48;
        xs_s[t * 68 + c] = x[c * CS + base + t * TS];
    }
    __syncthreads();
    const int t = lane;
    float xr[64];
    if (t < 48) {
        const float4* row = (const float4*)&xs_s[t * 68];
#pragma unroll
        for (int q = 0; q < 16; q++) {
            float4 v = row[q];
            xr[4*q+0]=v.x; xr[4*q+1]=v.y; xr[4*q+2]=v.z; xr[4*q+3]=v.w;
        }
        float m = 0.f;
#pragma unroll
        for (int c = 0; c < 64; c++) m += xr[c];
        m *= (1.0f / 64.0f);
        float var = 0.f;
#pragma unroll
        for (int c = 0; c < 64; c++) { float d0 = xr[c] - m; var += d0 * d0; }
        var *= (1.0f / 64.0f);
        float rs = rsqrtf(var + 1e-5f);
#pragma unroll
        for (int c = 0; c < 64; c++)
            xr[c] = (xr[c] - m) * rs * ln_g[DIR * 64 + c] + ln_b[DIR * 64 + c];
    }
    __syncthreads();
    if (t < 48 && wv == 0) {
        float4* row = (float4*)&xs_s[t * 68];
#pragma unroll
        for (int q = 0; q < 16; q++) {
            float4 v; v.x=xr[4*q+0]; v.y=xr[4*q+1]; v.z=xr[4*q+2]; v.w=xr[4*q+3];
            row[q] = v;
        }
    }
    if (t < 48) {
        for (int jj = 0; jj < 64; jj++) {
            int j = wv * 64 + jj;
            const float4* wrow = (const float4*)(ip + j * 64);
            float acc = 0.f;
#pragma unroll
            for (int q = 0; q < 16; q++) {
                float4 w4 = wrow[q];
                acc += xr[4*q+0]*w4.x + xr[4*q+1]*w4.y + xr[4*q+2]*w4.z + xr[4*q+3]*w4.w;
            }
            int col = (((j >> 2) ^ (t & 7)) << 2) | (j & 3);
            u_s[t * 128 + col] = acc;
        }
    }
    __syncthreads();
    {
        const int d = tid;
        float4 cw = *(const float4*)(conv_w + DIR * 512 + d * 4);
        float cb = conv_b[DIR * 128 + d];
        float w0 = 0.f, w1 = 0.f, w2 = 0.f;
        for (int tt = 0; tt < 48; tt++) {
            int col = tt * 128 + ((((d >> 2) ^ (tt & 7)) << 2) | (d & 3));
            float w3 = u_s[col];
            float xc = cw.x*w0 + cw.y*w1 + cw.z*w2 + cw.w*w3 + cb;
            u_s[col] = fast_silu(xc);
            w0 = w1; w1 = w2; w2 = w3;
        }
    }
    __syncthreads();
    if (t < 48) {
        float ur[128];
        const float4* urow = (const float4*)&u_s[t * 128];
#pragma unroll
        for (int g = 0; g < 32; g++) {
            float4 v = urow[g ^ (t & 7)];
            ur[4*g]=v.x; ur[4*g+1]=v.y; ur[4*g+2]=v.z; ur[4*g+3]=v.w;
        }
        for (int jj = 0; jj < 18; jj++) {
            int j = wv * 18 + jj;
            const float4* wrow = (const float4*)(xp + j * 128);
            float acc = 0.f;
#pragma unroll
            for (int q = 0; q < 32; q++) {
                float4 w4 = wrow[q];
                acc += ur[4*q]*w4.x + ur[4*q+1]*w4.y + ur[4*q+2]*w4.z + ur[4*q+3]*w4.w;
            }
            xd_s[t * 40 + j] = acc;
        }
    }
    __syncthreads();
    {
        const int d = tid;
        float A2[16]; bool powok = true;
#pragma unroll
        for (int n = 0; n < 16; n++) {
            float a = -__expf(A_log[DIR * 2048 + d * 16 + n]);
            powok = powok && (fabsf(a + (float)(n + 1)) < 1e-3f);
            A2[n] = a * 1.44269504088896340736f;
        }
        float4 dtw = *(const float4*)(dt_w + DIR * 512 + d * 4);
        float dtbv = dt_b[DIR * 128 + d];
        float dsv = D_ssm[DIR * 128 + d];
        float h[16];
#pragma unroll
        for (int n = 0; n < 16; n++) h[n] = 0.f;
#define SCAN_BODY(EXP_BLOCK)                                                   \
        for (int tt = 0; tt < 48; tt++) {                                      \
            const float* xrow = &xd_s[tt * 40];                                \
            float4 dl4 = *(const float4*)xrow;                                 \
            float dl = dtbv + dtw.x*dl4.x + dtw.y*dl4.y + dtw.z*dl4.z + dtw.w*dl4.w; \
            float delta = (dl > 20.f) ? dl : log1pf(__expf(dl));               \
            int col = tt * 128 + ((((d >> 2) ^ (tt & 7)) << 2) | (d & 3));     \
            float uu = u_s[col];                                               \
            float du = delta * uu;                                             \
            float e[16];                                                       \
            EXP_BLOCK                                                          \
            float4 Bv0 = *(const float4*)(xrow + 4);                           \
            float4 Bv1 = *(const float4*)(xrow + 8);                           \
            float4 Bv2 = *(const float4*)(xrow + 12);                          \
            float4 Bv3 = *(const float4*)(xrow + 16);                          \
            float4 Cv0 = *(const float4*)(xrow + 20);                          \
            float4 Cv1 = *(const float4*)(xrow + 24);                          \
            float4 Cv2 = *(const float4*)(xrow + 28);                          \
            float4 Cv3 = *(const float4*)(xrow + 32);                          \
            float Bf[16] = {Bv0.x,Bv0.y,Bv0.z,Bv0.w, Bv1.x,Bv1.y,Bv1.z,Bv1.w,  \
                            Bv2.x,Bv2.y,Bv2.z,Bv2.w, Bv3.x,Bv3.y,Bv3.z,Bv3.w}; \
            float Cf[16] = {Cv0.x,Cv0.y,Cv0.z,Cv0.w, Cv1.x,Cv1.y,Cv1.z,Cv1.w,  \
                            Cv2.x,Cv2.y,Cv2.z,Cv2.w, Cv3.x,Cv3.y,Cv3.z,Cv3.w}; \
            float y = 0.f;                                                     \
            _Pragma("unroll")                                                  \
            for (int n = 0; n < 16; n++) {                                     \
                h[n] = e[n] * h[n] + du * Bf[n];                               \
                y += h[n] * Cf[n];                                             \
            }                                                                  \
            u_s[col] = y + uu * dsv;                                           \
        }
        if (powok) {
            SCAN_BODY({
                float p = exp2f(-delta * 1.44269504088896340736f);
                e[0] = p;
                _Pragma("unroll")
                for (int n = 1; n < 16; n++) e[n] = e[n-1] * p;
            })
        } else {
            SCAN_BODY({
                _Pragma("unroll")
                for (int n = 0; n < 16; n++) e[n] = exp2f(delta * A2[n]);
            })
        }
#undef SCAN_BODY
    }
    {
        const int d = tid;
        float wr[64];
        const float4* wrow = (const float4*)(ip + (128 + d) * 64);
#pragma unroll
        for (int q = 0; q < 16; q++) {
            float4 v = wrow[q];
            wr[4*q]=v.x; wr[4*q+1]=v.y; wr[4*q+2]=v.z; wr[4*q+3]=v.w;
        }
        for (int tt = 0; tt < 48; tt++) {
            const float4* xrow = (const float4*)&xs_s[tt * 68];
            float acc = 0.f;
#pragma unroll
            for (int q = 0; q < 16; q++) {
                float4 v = xrow[q];
                acc += v.x*wr[4*q] + v.y*wr[4*q+1] + v.z*wr[4*q+2] + v.w*wr[4*q+3];
            }
            int col = tt * 128 + ((((d >> 2) ^ (tt & 7)) << 2) | (d & 3));
            u_s[col] = u_s[col] * fast_silu(acc);
        }
    }
    __syncthreads();
    if (t < 48) {
        float zr[128];
        const float4* zrow = (const float4*)&u_s[t * 128];
#pragma unroll
        for (int g = 0; g < 32; g++) {
            float4 v = zrow[g ^ (t & 7)];
            zr[4*g]=v.x; zr[4*g+1]=v.y; zr[4*g+2]=v.z; zr[4*g+3]=v.w;
        }
        for (int cc = 0; cc < 32; cc++) {
            int c = wv * 32 + cc;
            const float4* wrow = (const float4*)(op + c * 128);
            float acc = 0.f;
#pragma unroll
            for (int q = 0; q < 32; q++) {
                float4 w4 = wrow[q];
                acc += zr[4*q]*w4.x + zr[4*q+1]*w4.y + zr[4*q+2]*w4.z + zr[4*q+3]*w4.w;
            }
            int oaddr = c * CS + base + t * TS;
            float vout = wdir * acc;
            if (!FIRST) vout += out[oaddr];
            out[oaddr] = vout;
        }
    }
}

// ------------------------------------------------------------- launch -----
extern "C" void kernel_launch(void* const* d_in, const int* in_sizes, int n_in,
                              void* d_out, int out_size, void* d_ws, size_t ws_size,
                              hipStream_t stream) {
    const float* x        = (const float*)d_in[0];
    const float* in_proj  = (const float*)d_in[1];
    const float* conv_w   = (const float*)d_in[2];
    const float* conv_b   = (const float*)d_in[3];
    const float* x_proj   = (const float*)d_in[4];
    const float* dt_w     = (const float*)d_in[5];
    const float* dt_b     = (const float*)d_in[6];
    const float* A_log    = (const float*)d_in[7];
    const float* D_ssm    = (const float*)d_in[8];
    const float* out_proj = (const float*)d_in[9];
    const float* ln_g     = (const float*)d_in[10];
    const float* ln_b     = (const float*)d_in[11];
    const float* alpha    = (const float*)d_in[12];
    float* out = (float*)d_out;
    float* ws  = (float*)d_ws;

    if (ws_size >= (size_t)WS_FLOATS * 4) {
        prep_kernel<<<288, 256, 0, stream>>>(in_proj, out_proj, ws);

        k1_lnproj<0><<<1728, 256, 0, stream>>>(x, ln_g, ln_b, ws);
        k2_scan<0><<<2304, 128, 0, stream>>>(conv_w, conv_b, x_proj, dt_w, dt_b, A_log, D_ssm, ws);
        k3_outproj<0, true ><<<2304, 128, 0, stream>>>(x, ln_g, ln_b, alpha, ws, out);

        k1_lnproj<1><<<1728, 256, 0, stream>>>(x, ln_g, ln_b, ws);
        k2_scan<1><<<2304, 128, 0, stream>>>(conv_w, conv_b, x_proj, dt_w, dt_b, A_log, D_ssm, ws);
        k3_outproj<1, false><<<2304, 128, 0, stream>>>(x, ln_g, ln_b, alpha, ws, out);

        k1_lnproj<2><<<1728, 256, 0, stream>>>(x, ln_g, ln_b, ws);
        k2_scan<2><<<2304, 128, 0, stream>>>(conv_w, conv_b, x_proj, dt_w, dt_b, A_log, D_ssm, ws);
        k3_outproj<2, false><<<2304, 128, 0, stream>>>(x, ln_g, ln_b, alpha, ws, out);
    } else {
        dim3 grid(2304), block(128);
        mamba_dir_v1<0, true ><<<grid, block, 0, stream>>>(x, in_proj, conv_w, conv_b, x_proj,
            dt_w, dt_b, A_log, D_ssm, out_proj, ln_g, ln_b, alpha, out);
        mamba_dir_v1<1, false><<<grid, block, 0, stream>>>(x, in_proj, conv_w, conv_b, x_proj,
            dt_w, dt_b, A_log, D_ssm, out_proj, ln_g, ln_b, alpha, out);
        mamba_dir_v1<2, false><<<grid, block, 0, stream>>>(x, in_proj, conv_w, conv_b, x_proj,
            dt_w, dt_b, A_log, D_ssm, out_proj, ln_g, ln_b, alpha, out);
    }
}

// Round 6
// 1123.057 us; speedup vs baseline: 1.0115x; 1.0115x over previous
//
#include <hip/hip_runtime.h>
#include <math.h>

// TriDirectionalMamba: C=64, N=16, DI=128, K=4, DT_RANK=4, L=48, 48^3, B=1.
// v6: cross-direction merged pipeline (big-ws path):
//   prep_big: ipTg = g(.)*in_proj^T (LN gamma folded), S1/S2 fold vectors,
//             opT transpose.
//   k1_all:   stage x tile once, LN stats once, 3 folded GEMMs -> tb[dir]
//   k2_all:   grid 6912, dir = bid/2304; per-seq conv+x_proj+scan (v5 body)
//   k3_all:   stage x once, stats once, 3x(res GEMM+gate+out_proj) weighted
//             accumulate in LDS, single pure write of out (no RMW).
// Needs 3 tb buffers (170.2 MB). Fallback: v5 per-dir path (proven, 114 MB).

#define CS   110592                        // channel stride in x
#define TBF  (110592 * 128)                // one tb buffer, floats

// ---- big-path ws layout (floats) ----
#define IPTG_OFF (3 * TBF)
#define S1_OFF   (IPTG_OFF + 3 * 64 * 256)
#define S2_OFF   (S1_OFF + 3 * 256)
#define OPTB_OFF (S2_OFF + 3 * 256)
#define WS_BIG   (OPTB_OFF + 3 * 128 * 64)

// ---- small-path (v5) ws layout (floats) ----
#define IPT_OFF  TBF
#define OPT_OFF  (IPT_OFF + 3 * 64 * 256)
#define WS_SMALL (OPT_OFF + 3 * 128 * 64)

__device__ __forceinline__ float fast_silu(float x) {
    return x / (1.0f + __expf(-x));
}
// branchless stable softplus: max(x,0) + log(1+exp(-|x|))
__device__ __forceinline__ float softplus_f(float x) {
    float em = __expf(-fabsf(x));
    return fmaxf(x, 0.f) + __logf(1.f + em);
}

// ============================ BIG PATH =====================================

__global__ void prep_big(const float* __restrict__ ip,
                         const float* __restrict__ op,
                         const float* __restrict__ ln_g,
                         float* __restrict__ ws)
{
    float* ipTg = ws + IPTG_OFF;   // [dir][c][256], gamma folded
    float* opT  = ws + OPTB_OFF;   // [dir][dch][64]
    int i = blockIdx.x * 256 + threadIdx.x;
    if (i < 3 * 256 * 64) {
        int dir = i / 16384, r = i % 16384, j = r / 64, c = r % 64;
        ipTg[dir * 16384 + c * 256 + j] = ip[i] * ln_g[dir * 64 + c];
    } else {
        int k = i - 3 * 256 * 64;
        if (k < 3 * 64 * 128) {
            int dir = k / 8192, r = k % 8192, c = r / 128, dch = r % 128;
            opT[dir * 8192 + dch * 64 + c] = op[k];
        }
    }
}

// S1[dir][j] = sum_c g_c W[j][c] ; S2[dir][j] = sum_c b_c W[j][c]
__global__ void prep_s12(const float* __restrict__ ip,
                         const float* __restrict__ ln_g,
                         const float* __restrict__ ln_b,
                         float* __restrict__ ws)
{
    const int dir = blockIdx.x, j = threadIdx.x;
    const float* W = ip + dir * 16384 + j * 64;
    float s1 = 0.f, s2 = 0.f;
#pragma unroll 8
    for (int c = 0; c < 64; c++) {
        s1 += ln_g[dir * 64 + c] * W[c];
        s2 += ln_b[dir * 64 + c] * W[c];
    }
    ws[S1_OFF + dir * 256 + j] = s1;
    ws[S2_OFF + dir * 256 + j] = s2;
}

// --------------------------------------------------------------- k1_all ----
// Block = 64 consecutive output tokens, 256 threads. Stage raw x once,
// LN stats once, 3 folded GEMMs -> tb[dir][p][128] (xin halves only).
__global__ __launch_bounds__(256, 4)
void k1_all(const float* __restrict__ x, float* __restrict__ ws)
{
    __shared__ float Xs[64 * 64];    // [c][tok] raw
    __shared__ float ms[64], rss[64];
    const int tid = threadIdx.x;
    const int p0 = blockIdx.x * 64;

    {
        const int c0 = tid >> 6, j = tid & 63;
#pragma unroll
        for (int cc = 0; cc < 16; cc++) {
            int c = cc * 4 + c0;
            Xs[c * 64 + j] = x[c * CS + p0 + j];
        }
    }
    __syncthreads();

    if (tid < 64) {
        float s1 = 0.f, s2 = 0.f;
#pragma unroll
        for (int c = 0; c < 64; c++) {
            float v = Xs[c * 64 + tid];
            s1 += v; s2 += v * v;
        }
        float m = s1 * (1.f / 64.f);
        ms[tid]  = m;
        rss[tid] = rsqrtf(s2 * (1.f / 64.f) - m * m + 1e-5f);
    }
    __syncthreads();

    const int ch = tid & 127, half = tid >> 7;
#pragma unroll
    for (int dir = 0; dir < 3; dir++) {
        const float* ipTg = ws + IPTG_OFF + dir * 16384;
        const float S1v = ws[S1_OFF + dir * 256 + ch];
        const float S2v = ws[S2_OFF + dir * 256 + ch];
        float* tb = ws + (size_t)dir * TBF;

        float wgt[64];
#pragma unroll
        for (int c = 0; c < 64; c++) wgt[c] = ipTg[c * 256 + ch];

#pragma unroll
        for (int gg = 0; gg < 2; gg++) {
            int g = half * 2 + gg;
            float acc[16];
#pragma unroll
            for (int i = 0; i < 16; i++) acc[i] = 0.f;
#pragma unroll 8
            for (int c = 0; c < 64; c++) {
                const float4* xr = (const float4*)&Xs[c * 64 + g * 16];
                float4 x0 = xr[0], x1 = xr[1], x2 = xr[2], x3 = xr[3];
                float wv = wgt[c];
                acc[0]  += x0.x * wv; acc[1]  += x0.y * wv;
                acc[2]  += x0.z * wv; acc[3]  += x0.w * wv;
                acc[4]  += x1.x * wv; acc[5]  += x1.y * wv;
                acc[6]  += x1.z * wv; acc[7]  += x1.w * wv;
                acc[8]  += x2.x * wv; acc[9]  += x2.y * wv;
                acc[10] += x2.z * wv; acc[11] += x2.w * wv;
                acc[12] += x3.x * wv; acc[13] += x3.y * wv;
                acc[14] += x3.z * wv; acc[15] += x3.w * wv;
            }
#pragma unroll
            for (int i = 0; i < 16; i++) {
                int tok = g * 16 + i;
                float val = rss[tok] * (acc[i] - ms[tok] * S1v) + S2v;
                tb[(size_t)(p0 + tok) * 128 + ch] = val;
            }
        }
    }
}

// --------------------------------------------------------------- k2_all ----
// Grid 6912 = 3 dirs x 2304 seqs; block = one sequence (128 thr). v5 body.
__global__ __launch_bounds__(128, 2)
void k2_all(const float* __restrict__ conv_w,
            const float* __restrict__ conv_b,
            const float* __restrict__ x_proj,
            const float* __restrict__ dt_w,
            const float* __restrict__ dt_b,
            const float* __restrict__ A_log,
            const float* __restrict__ D_ssm,
            float* __restrict__ ws)
{
    __shared__ float u_s[48 * 128];
    __shared__ float xd_s[48 * 36];
    const int tid = threadIdx.x;
    const int bid = blockIdx.x;
    const int dir = bid / 2304;
    const int s   = bid - dir * 2304;
    float* tb = ws + (size_t)dir * TBF;

    int base, TS;
    if (dir == 0)      { base = s;                               TS = 2304; }
    else if (dir == 1) { base = (s / 48) * 2304 + (s % 48);      TS = 48;   }
    else               { base = (s / 48) * 2304 + (s % 48) * 48; TS = 1;    }

    // --- phase A: depthwise causal conv + silu (thread = d) ---
    {
        const int d = tid;
        float xin[48];
#pragma unroll
        for (int t = 0; t < 48; t++)
            xin[t] = tb[(size_t)(base + t * TS) * 128 + d];
        float4 cw = *(const float4*)(conv_w + dir * 512 + d * 4);
        float cb  = conv_b[dir * 128 + d];
#pragma unroll
        for (int t = 0; t < 48; t++) {
            float a0 = (t >= 3) ? xin[t-3] : 0.f;
            float a1 = (t >= 2) ? xin[t-2] : 0.f;
            float a2 = (t >= 1) ? xin[t-1] : 0.f;
            float v = cw.x * a0 + cw.y * a1 + cw.z * a2 + cw.w * xin[t] + cb;
            u_s[t * 128 + (((((d >> 2) ^ (t & 7))) << 2) | (d & 3))] = fast_silu(v);
        }
    }
    __syncthreads();

    // --- phase B: x_proj u(128)->x_dbl(36); lane=t, j split by wave ---
    {
        const int t  = tid & 63;
        const int wv = __builtin_amdgcn_readfirstlane(tid >> 6);
        const int tr = (t < 48) ? t : 47;
        const int sw = tr & 7;
        float acc[18];
#pragma unroll
        for (int j = 0; j < 18; j++) acc[j] = 0.f;
        const float* xpw = x_proj + dir * 36 * 128 + (wv * 18) * 128;
        const float4* urow = (const float4*)&u_s[tr * 128];
#pragma unroll
        for (int qc = 0; qc < 4; qc++) {
            float4 u4[8];
#pragma unroll
            for (int q = 0; q < 8; q++) u4[q] = urow[qc * 8 + (q ^ sw)];
#pragma unroll
            for (int j = 0; j < 18; j++) {
                const float4* wr = (const float4*)(xpw + j * 128 + qc * 32);
                float a0 = 0.f, a1 = 0.f, a2 = 0.f, a3 = 0.f;
#pragma unroll
                for (int q = 0; q < 8; q++) {
                    float4 w4 = wr[q];
                    a0 += u4[q].x * w4.x; a1 += u4[q].y * w4.y;
                    a2 += u4[q].z * w4.z; a3 += u4[q].w * w4.w;
                }
                acc[j] += (a0 + a1) + (a2 + a3);
            }
        }
        if (t < 48) {
#pragma unroll
            for (int j = 0; j < 18; j++) xd_s[t * 36 + wv * 18 + j] = acc[j];
        }
    }
    __syncthreads();

    // --- phase C: selective scan (thread = d) ---
    {
        const int d = tid;
        float A[16];
        {
            const float4* al = (const float4*)(A_log + dir * 2048 + d * 16);
#pragma unroll
            for (int q = 0; q < 4; q++) {
                float4 v = al[q];
                A[4*q+0] = -__expf(v.x); A[4*q+1] = -__expf(v.y);
                A[4*q+2] = -__expf(v.z); A[4*q+3] = -__expf(v.w);
            }
        }
        float4 dtw = *(const float4*)(dt_w + dir * 512 + d * 4);
        float dtbv = dt_b[dir * 128 + d];
        float dsv  = D_ssm[dir * 128 + d];
        float h[16];
#pragma unroll
        for (int n = 0; n < 16; n++) h[n] = 0.f;

        const int dsw_hi = d >> 2, dlo = d & 3;
        for (int tt = 0; tt < 48; tt++) {
            const float4* xr4 = (const float4*)&xd_s[tt * 36];
            float4 R0 = xr4[0];
            float uu = u_s[tt * 128 + (((dsw_hi ^ (tt & 7)) << 2) | dlo)];
            float dl = dtbv + dtw.x*R0.x + dtw.y*R0.y + dtw.z*R0.z + dtw.w*R0.w;
            float delta = softplus_f(dl);
            float du = delta * uu;
            float4 B0 = xr4[1], B1 = xr4[2], B2 = xr4[3], B3 = xr4[4];
            float4 C0 = xr4[5], C1 = xr4[6], C2 = xr4[7], C3 = xr4[8];
            float y0 = 0.f, y1 = 0.f, y2 = 0.f, y3 = 0.f;
#define HN(n, Bc, Cc, ya) { float e = __expf(delta * A[n]); \
            h[n] = e * h[n] + du * (Bc); ya += h[n] * (Cc); }
            HN(0,  B0.x, C0.x, y0) HN(1,  B0.y, C0.y, y1)
            HN(2,  B0.z, C0.z, y2) HN(3,  B0.w, C0.w, y3)
            HN(4,  B1.x, C1.x, y0) HN(5,  B1.y, C1.y, y1)
            HN(6,  B1.z, C1.z, y2) HN(7,  B1.w, C1.w, y3)
            HN(8,  B2.x, C2.x, y0) HN(9,  B2.y, C2.y, y1)
            HN(10, B2.z, C2.z, y2) HN(11, B2.w, C2.w, y3)
            HN(12, B3.x, C3.x, y0) HN(13, B3.y, C3.y, y1)
            HN(14, B3.z, C3.z, y2) HN(15, B3.w, C3.w, y3)
#undef HN
            tb[(size_t)(base + tt * TS) * 128 + d] =
                ((y0 + y1) + (y2 + y3)) + uu * dsv;
        }
    }
}

// --------------------------------------------------------------- k3_all ----
// Block = 48 consecutive output tokens (d_sp,h). Stage x once, stats once,
// 3x(res GEMM [folded LN] + gate + out_proj) weighted-accumulated in LDS,
// single pure write of out.
__global__ __launch_bounds__(128, 3)
void k3_all(const float* __restrict__ x,
            const float* __restrict__ alpha,
            float* __restrict__ ws,
            float* __restrict__ out)
{
    __shared__ float xs[64 * 52];    // raw x tile [c][w]
    __shared__ float sb[48 * 132];   // gated z [w][d]
    __shared__ float outA[64 * 49];  // weighted out accumulator [c][w]
    __shared__ float ms[48], rss[48];
    const int tid = threadIdx.x;
    const int b = blockIdx.x;
    const int d_sp = b / 48;
    const int h = b - d_sp * 48;
    const int obase = d_sp * 2304 + h * 48;

    float a0 = alpha[0], a1 = alpha[1], a2 = alpha[2];
    float mx = fmaxf(a0, fmaxf(a1, a2));
    float e0 = __expf(a0 - mx), e1 = __expf(a1 - mx), e2 = __expf(a2 - mx);
    float esum = e0 + e1 + e2;
    float wv3[3] = { e0 / esum, e1 / esum, e2 / esum };

    for (int o = tid; o < 64 * 48; o += 128) {
        int c = o / 48, w = o - c * 48;
        xs[c * 52 + w] = x[c * CS + obase + w];
    }
    __syncthreads();

    if (tid < 48) {
        const int w = tid;
        float s1 = 0.f, s2 = 0.f;
#pragma unroll
        for (int c = 0; c < 64; c++) {
            float v = xs[c * 52 + w];
            s1 += v; s2 += v * v;
        }
        float m = s1 * (1.f / 64.f);
        ms[w]  = m;
        rss[w] = rsqrtf(s2 * (1.f / 64.f) - m * m + 1e-5f);
    }
    __syncthreads();

    const int cp = tid & 31;
    const int wg = tid >> 5;

#pragma unroll
    for (int dir = 0; dir < 3; dir++) {
        // --- res GEMM (folded LN) + gate (thread = d) ---
        {
            const int d = tid;
            const float* ipTg = ws + IPTG_OFF + dir * 16384;
            const float S1v = ws[S1_OFF + dir * 256 + 128 + d];
            const float S2v = ws[S2_OFF + dir * 256 + 128 + d];
            const float* tb = ws + (size_t)dir * TBF;
            float wgt2[64];
#pragma unroll
            for (int c = 0; c < 64; c++) wgt2[c] = ipTg[c * 256 + 128 + d];
#pragma unroll
            for (int wb = 0; wb < 4; wb++) {
                float acc[12];
#pragma unroll
                for (int i = 0; i < 12; i++) acc[i] = 0.f;
#pragma unroll 8
                for (int c = 0; c < 64; c++) {
                    const float4* xr = (const float4*)&xs[c * 52 + wb * 12];
                    float4 v0 = xr[0], v1 = xr[1], v2 = xr[2];
                    float wv = wgt2[c];
                    acc[0] += v0.x * wv; acc[1] += v0.y * wv;
                    acc[2] += v0.z * wv; acc[3] += v0.w * wv;
                    acc[4] += v1.x * wv; acc[5] += v1.y * wv;
                    acc[6] += v1.z * wv; acc[7] += v1.w * wv;
                    acc[8] += v2.x * wv; acc[9] += v2.y * wv;
                    acc[10] += v2.z * wv; acc[11] += v2.w * wv;
                }
#pragma unroll
                for (int i = 0; i < 12; i++) {
                    int w = wb * 12 + i;
                    float res = rss[w] * (acc[i] - ms[w] * S1v) + S2v;
                    float zv = tb[(size_t)(obase + w) * 128 + d];
                    sb[w * 132 + d] = zv * fast_silu(res);
                }
            }
        }
        __syncthreads();

        // --- out_proj, weighted accumulate into outA ---
        {
            const float* opT = ws + OPTB_OFF + dir * 8192;
            float acc0[12], acc1[12];
#pragma unroll
            for (int i = 0; i < 12; i++) { acc0[i] = 0.f; acc1[i] = 0.f; }
#pragma unroll 2
            for (int dc = 0; dc < 32; dc++) {
                float w0[4], w1[4];
#pragma unroll
                for (int i = 0; i < 4; i++) {
                    w0[i] = opT[(dc * 4 + i) * 64 + cp];
                    w1[i] = opT[(dc * 4 + i) * 64 + cp + 32];
                }
#pragma unroll
                for (int i = 0; i < 12; i++) {
                    int w = wg * 12 + i;
                    float4 z4 = *(const float4*)&sb[w * 132 + dc * 4];
                    acc0[i] += z4.x * w0[0] + z4.y * w0[1] + z4.z * w0[2] + z4.w * w0[3];
                    acc1[i] += z4.x * w1[0] + z4.y * w1[1] + z4.z * w1[2] + z4.w * w1[3];
                }
            }
            float wd = wv3[dir];
            if (dir == 0) {
#pragma unroll
                for (int i = 0; i < 12; i++) {
                    int w = wg * 12 + i;
                    outA[cp * 49 + w]        = wd * acc0[i];
                    outA[(cp + 32) * 49 + w] = wd * acc1[i];
                }
            } else {
#pragma unroll
                for (int i = 0; i < 12; i++) {
                    int w = wg * 12 + i;
                    outA[cp * 49 + w]        += wd * acc0[i];
                    outA[(cp + 32) * 49 + w] += wd * acc1[i];
                }
            }
        }
        __syncthreads();   // sb reuse next dir; outA complete after last dir
    }

    for (int o = tid; o < 3072; o += 128) {
        int c = o / 48, w = o - c * 48;
        out[c * CS + obase + w] = outA[c * 49 + w];
    }
}

// ====================== SMALL PATH (v5, proven) ============================

__global__ void prep_kernel(const float* __restrict__ ip,
                            const float* __restrict__ op,
                            float* __restrict__ ws)
{
    float* ipT = ws + IPT_OFF;
    float* opT = ws + OPT_OFF;
    int i = blockIdx.x * 256 + threadIdx.x;
    if (i < 3 * 256 * 64) {
        int dir = i / 16384, r = i % 16384, j = r / 64, c = r % 64;
        ipT[dir * 16384 + c * 256 + j] = ip[i];
    } else {
        int k = i - 3 * 256 * 64;
        if (k < 3 * 64 * 128) {
            int dir = k / 8192, r = k % 8192, c = r / 128, dch = r % 128;
            opT[dir * 8192 + dch * 64 + c] = op[k];
        }
    }
}

template<int DIR>
__global__ __launch_bounds__(256, 4)
void k1_lnproj(const float* __restrict__ x,
               const float* __restrict__ ln_g,
               const float* __restrict__ ln_b,
               float* __restrict__ ws)
{
    __shared__ float Xs[64 * 64];
    const float* ipT = ws + IPT_OFF + DIR * 16384;
    float* tb = ws;
    const int tid = threadIdx.x;
    const int p0 = blockIdx.x * 64;
    {
        const int c0 = tid >> 6, j = tid & 63;
#pragma unroll
        for (int cc = 0; cc < 16; cc++) {
            int c = cc * 4 + c0;
            Xs[c * 64 + j] = x[c * CS + p0 + j];
        }
    }
    __syncthreads();
    if (tid < 64) {
        float s1 = 0.f, s2 = 0.f;
#pragma unroll
        for (int c = 0; c < 64; c++) {
            float v = Xs[c * 64 + tid];
            s1 += v; s2 += v * v;
        }
        float m  = s1 * (1.f / 64.f);
        float rs = rsqrtf(s2 * (1.f / 64.f) - m * m + 1e-5f);
#pragma unroll
        for (int c = 0; c < 64; c++) {
            Xs[c * 64 + tid] = (Xs[c * 64 + tid] - m) * rs * ln_g[DIR * 64 + c]
                               + ln_b[DIR * 64 + c];
        }
    }
    __syncthreads();
    const int ch = tid & 127, half = tid >> 7;
    float wgt[64];
#pragma unroll
    for (int c = 0; c < 64; c++) wgt[c] = ipT[c * 256 + ch];
#pragma unroll
    for (int gg = 0; gg < 2; gg++) {
        int g = half * 2 + gg;
        float acc[16];
#pragma unroll
        for (int i = 0; i < 16; i++) acc[i] = 0.f;
#pragma unroll 8
        for (int c = 0; c < 64; c++) {
            const float4* xr = (const float4*)&Xs[c * 64 + g * 16];
            float4 x0 = xr[0], x1 = xr[1], x2 = xr[2], x3 = xr[3];
            float wv = wgt[c];
            acc[0]  += x0.x * wv; acc[1]  += x0.y * wv;
            acc[2]  += x0.z * wv; acc[3]  += x0.w * wv;
            acc[4]  += x1.x * wv; acc[5]  += x1.y * wv;
            acc[6]  += x1.z * wv; acc[7]  += x1.w * wv;
            acc[8]  += x2.x * wv; acc[9]  += x2.y * wv;
            acc[10] += x2.z * wv; acc[11] += x2.w * wv;
            acc[12] += x3.x * wv; acc[13] += x3.y * wv;
            acc[14] += x3.z * wv; acc[15] += x3.w * wv;
        }
#pragma unroll
        for (int i = 0; i < 16; i++)
            tb[(size_t)(p0 + g * 16 + i) * 128 + ch] = acc[i];
    }
}

template<int DIR>
__global__ __launch_bounds__(128, 2)
void k2_scan(const float* __restrict__ conv_w,
             const float* __restrict__ conv_b,
             const float* __restrict__ x_proj,
             const float* __restrict__ dt_w,
             const float* __restrict__ dt_b,
             const float* __restrict__ A_log,
             const float* __restrict__ D_ssm,
             float* __restrict__ ws)
{
    __shared__ float u_s[48 * 128];
    __shared__ float xd_s[48 * 36];
    float* tb = ws;
    const int tid = threadIdx.x;
    const int s = blockIdx.x;
    int base, TS;
    if (DIR == 0)      { base = s;                               TS = 2304; }
    else if (DIR == 1) { base = (s / 48) * 2304 + (s % 48);      TS = 48;   }
    else               { base = (s / 48) * 2304 + (s % 48) * 48; TS = 1;    }
    {
        const int d = tid;
        float xin[48];
#pragma unroll
        for (int t = 0; t < 48; t++)
            xin[t] = tb[(size_t)(base + t * TS) * 128 + d];
        float4 cw = *(const float4*)(conv_w + DIR * 512 + d * 4);
        float cb  = conv_b[DIR * 128 + d];
#pragma unroll
        for (int t = 0; t < 48; t++) {
            float a0 = (t >= 3) ? xin[t-3] : 0.f;
            float a1 = (t >= 2) ? xin[t-2] : 0.f;
            float a2 = (t >= 1) ? xin[t-1] : 0.f;
            float v = cw.x * a0 + cw.y * a1 + cw.z * a2 + cw.w * xin[t] + cb;
            u_s[t * 128 + (((((d >> 2) ^ (t & 7))) << 2) | (d & 3))] = fast_silu(v);
        }
    }
    __syncthreads();
    {
        const int t  = tid & 63;
        const int wv = __builtin_amdgcn_readfirstlane(tid >> 6);
        const int tr = (t < 48) ? t : 47;
        const int sw = tr & 7;
        float acc[18];
#pragma unroll
        for (int j = 0; j < 18; j++) acc[j] = 0.f;
        const float* xpw = x_proj + DIR * 36 * 128 + (wv * 18) * 128;
        const float4* urow = (const float4*)&u_s[tr * 128];
#pragma unroll
        for (int qc = 0; qc < 4; qc++) {
            float4 u4[8];
#pragma unroll
            for (int q = 0; q < 8; q++) u4[q] = urow[qc * 8 + (q ^ sw)];
#pragma unroll
            for (int j = 0; j < 18; j++) {
                const float4* wr = (const float4*)(xpw + j * 128 + qc * 32);
                float a0 = 0.f, a1 = 0.f, a2 = 0.f, a3 = 0.f;
#pragma unroll
                for (int q = 0; q < 8; q++) {
                    float4 w4 = wr[q];
                    a0 += u4[q].x * w4.x; a1 += u4[q].y * w4.y;
                    a2 += u4[q].z * w4.z; a3 += u4[q].w * w4.w;
                }
                acc[j] += (a0 + a1) + (a2 + a3);
            }
        }
        if (t < 48) {
#pragma unroll
            for (int j = 0; j < 18; j++) xd_s[t * 36 + wv * 18 + j] = acc[j];
        }
    }
    __syncthreads();
    {
        const int d = tid;
        float A[16];
        {
            const float4* al = (const float4*)(A_log + DIR * 2048 + d * 16);
#pragma unroll
            for (int q = 0; q < 4; q++) {
                float4 v = al[q];
                A[4*q+0] = -__expf(v.x); A[4*q+1] = -__expf(v.y);
                A[4*q+2] = -__expf(v.z); A[4*q+3] = -__expf(v.w);
            }
        }
        float4 dtw = *(const float4*)(dt_w + DIR * 512 + d * 4);
        float dtbv = dt_b[DIR * 128 + d];
        float dsv  = D_ssm[DIR * 128 + d];
        float h[16];
#pragma unroll
        for (int n = 0; n < 16; n++) h[n] = 0.f;
        const int dsw_hi = d >> 2, dlo = d & 3;
        for (int tt = 0; tt < 48; tt++) {
            const float4* xr4 = (const float4*)&xd_s[tt * 36];
            float4 R0 = xr4[0];
            float uu = u_s[tt * 128 + (((dsw_hi ^ (tt & 7)) << 2) | dlo)];
            float dl = dtbv + dtw.x*R0.x + dtw.y*R0.y + dtw.z*R0.z + dtw.w*R0.w;
            float delta = softplus_f(dl);
            float du = delta * uu;
            float4 B0 = xr4[1], B1 = xr4[2], B2 = xr4[3], B3 = xr4[4];
            float4 C0 = xr4[5], C1 = xr4[6], C2 = xr4[7], C3 = xr4[8];
            float y0 = 0.f, y1 = 0.f, y2 = 0.f, y3 = 0.f;
#define HN(n, Bc, Cc, ya) { float e = __expf(delta * A[n]); \
            h[n] = e * h[n] + du * (Bc); ya += h[n] * (Cc); }
            HN(0,  B0.x, C0.x, y0) HN(1,  B0.y, C0.y, y1)
            HN(2,  B0.z, C0.z, y2) HN(3,  B0.w, C0.w, y3)
            HN(4,  B1.x, C1.x, y0) HN(5,  B1.y, C1.y, y1)
            HN(6,  B1.z, C1.z, y2) HN(7,  B1.w, C1.w, y3)
            HN(8,  B2.x, C2.x, y0) HN(9,  B2.y, C2.y, y1)
            HN(10, B2.z, C2.z, y2) HN(11, B2.w, C2.w, y3)
            HN(12, B3.x, C3.x, y0) HN(13, B3.y, C3.y, y1)
            HN(14, B3.z, C3.z, y2) HN(15, B3.w, C3.w, y3)
#undef HN
            tb[(size_t)(base + tt * TS) * 128 + d] =
                ((y0 + y1) + (y2 + y3)) + uu * dsv;
        }
    }
}

template<int DIR, bool FIRST>
__global__ __launch_bounds__(128, 4)
void k3_outproj(const float* __restrict__ x,
                const float* __restrict__ ln_g,
                const float* __restrict__ ln_b,
                const float* __restrict__ alpha,
                float* __restrict__ ws,
                float* __restrict__ out)
{
    __shared__ float sb[48 * 132];
    __shared__ float xs[64 * 52];
    float* tb = ws;
    const float* ipT = ws + IPT_OFF + DIR * 16384;
    const float* opT = ws + OPT_OFF + DIR * 8192;
    const int tid = threadIdx.x;
    const int b = blockIdx.x;
    const int d_sp = b / 48;
    const int h = b - d_sp * 48;
    const int obase = d_sp * 2304 + h * 48;
    float a0 = alpha[0], a1 = alpha[1], a2 = alpha[2];
    float mx = fmaxf(a0, fmaxf(a1, a2));
    float e0 = __expf(a0 - mx), e1 = __expf(a1 - mx), e2 = __expf(a2 - mx);
    float wdir = ((DIR == 0) ? e0 : (DIR == 1) ? e1 : e2) / (e0 + e1 + e2);
    for (int o = tid; o < 64 * 48; o += 128) {
        int c = o / 48, w = o - c * 48;
        xs[c * 52 + w] = x[c * CS + obase + w];
    }
    __syncthreads();
    if (tid < 48) {
        const int w = tid;
        float s1 = 0.f, s2 = 0.f;
#pragma unroll
        for (int c = 0; c < 64; c++) {
            float v = xs[c * 52 + w];
            s1 += v; s2 += v * v;
        }
        float m  = s1 * (1.f / 64.f);
        float rs = rsqrtf(s2 * (1.f / 64.f) - m * m + 1e-5f);
#pragma unroll
        for (int c = 0; c < 64; c++) {
            xs[c * 52 + w] = (xs[c * 52 + w] - m) * rs * ln_g[DIR * 64 + c]
                             + ln_b[DIR * 64 + c];
        }
    }
    __syncthreads();
    {
        const int d = tid;
        float wgt2[64];
#pragma unroll
        for (int c = 0; c < 64; c++) wgt2[c] = ipT[c * 256 + 128 + d];
#pragma unroll
        for (int wb = 0; wb < 4; wb++) {
            float acc[12];
#pragma unroll
            for (int i = 0; i < 12; i++) acc[i] = 0.f;
#pragma unroll 8
            for (int c = 0; c < 64; c++) {
                const float4* xr = (const float4*)&xs[c * 52 + wb * 12];
                float4 v0 = xr[0], v1 = xr[1], v2 = xr[2];
                float wv = wgt2[c];
                acc[0] += v0.x * wv; acc[1] += v0.y * wv;
                acc[2] += v0.z * wv; acc[3] += v0.w * wv;
                acc[4] += v1.x * wv; acc[5] += v1.y * wv;
                acc[6] += v1.z * wv; acc[7] += v1.w * wv;
                acc[8] += v2.x * wv; acc[9] += v2.y * wv;
                acc[10] += v2.z * wv; acc[11] += v2.w * wv;
            }
#pragma unroll
            for (int i = 0; i < 12; i++) {
                int w = wb * 12 + i;
                float zv = tb[(size_t)(obase + w) * 128 + d];
                sb[w * 132 + d] = zv * fast_silu(acc[i]);
            }
        }
    }
    __syncthreads();
    const int cp = tid & 31;
    const int wg = tid >> 5;
    float acc0[12], acc1[12];
#pragma unroll
    for (int i = 0; i < 12; i++) { acc0[i] = 0.f; acc1[i] = 0.f; }
#pragma unroll 2
    for (int dc = 0; dc < 32; dc++) {
        float w0[4], w1[4];
#pragma unroll
        for (int i = 0; i < 4; i++) {
            w0[i] = opT[(dc * 4 + i) * 64 + cp];
            w1[i] = opT[(dc * 4 + i) * 64 + cp + 32];
        }
#pragma unroll
        for (int i = 0; i < 12; i++) {
            int w = wg * 12 + i;
            float4 z4 = *(const float4*)&sb[w * 132 + dc * 4];
            acc0[i] += z4.x * w0[0] + z4.y * w0[1] + z4.z * w0[2] + z4.w * w0[3];
            acc1[i] += z4.x * w1[0] + z4.y * w1[1] + z4.z * w1[2] + z4.w * w1[3];
        }
    }
    __syncthreads();
#pragma unroll
    for (int i = 0; i < 12; i++) {
        int w = wg * 12 + i;
        sb[cp * 49 + w]        = acc0[i];
        sb[(cp + 32) * 49 + w] = acc1[i];
    }
    __syncthreads();
    for (int o = tid; o < 3072; o += 128) {
        int c = o / 48, w = o - c * 48;
        int addr = c * CS + obase + w;
        float val = wdir * sb[c * 49 + w];
        if (!FIRST) val += out[addr];
        out[addr] = val;
    }
}

// ------------------------------------------------------------- launch -----
extern "C" void kernel_launch(void* const* d_in, const int* in_sizes, int n_in,
                              void* d_out, int out_size, void* d_ws, size_t ws_size,
                              hipStream_t stream) {
    const float* x        = (const float*)d_in[0];
    const float* in_proj  = (const float*)d_in[1];
    const float* conv_w   = (const float*)d_in[2];
    const float* conv_b   = (const float*)d_in[3];
    const float* x_proj   = (const float*)d_in[4];
    const float* dt_w     = (const float*)d_in[5];
    const float* dt_b     = (const float*)d_in[6];
    const float* A_log    = (const float*)d_in[7];
    const float* D_ssm    = (const float*)d_in[8];
    const float* out_proj = (const float*)d_in[9];
    const float* ln_g     = (const float*)d_in[10];
    const float* ln_b     = (const float*)d_in[11];
    const float* alpha    = (const float*)d_in[12];
    float* out = (float*)d_out;
    float* ws  = (float*)d_ws;

    if (ws_size >= (size_t)WS_BIG * 4) {
        prep_big<<<288, 256, 0, stream>>>(in_proj, out_proj, ln_g, ws);
        prep_s12<<<3, 256, 0, stream>>>(in_proj, ln_g, ln_b, ws);
        k1_all<<<1728, 256, 0, stream>>>(x, ws);
        k2_all<<<6912, 128, 0, stream>>>(conv_w, conv_b, x_proj, dt_w, dt_b,
                                         A_log, D_ssm, ws);
        k3_all<<<2304, 128, 0, stream>>>(x, alpha, ws, out);
    } else {
        prep_kernel<<<288, 256, 0, stream>>>(in_proj, out_proj, ws);

        k1_lnproj<0><<<1728, 256, 0, stream>>>(x, ln_g, ln_b, ws);
        k2_scan<0><<<2304, 128, 0, stream>>>(conv_w, conv_b, x_proj, dt_w, dt_b, A_log, D_ssm, ws);
        k3_outproj<0, true ><<<2304, 128, 0, stream>>>(x, ln_g, ln_b, alpha, ws, out);

        k1_lnproj<1><<<1728, 256, 0, stream>>>(x, ln_g, ln_b, ws);
        k2_scan<1><<<2304, 128, 0, stream>>>(conv_w, conv_b, x_proj, dt_w, dt_b, A_log, D_ssm, ws);
        k3_outproj<1, false><<<2304, 128, 0, stream>>>(x, ln_g, ln_b, alpha, ws, out);

        k1_lnproj<2><<<1728, 256, 0, stream>>>(x, ln_g, ln_b, ws);
        k2_scan<2><<<2304, 128, 0, stream>>>(conv_w, conv_b, x_proj, dt_w, dt_b, A_log, D_ssm, ws);
        k3_outproj<2, false><<<2304, 128, 0, stream>>>(x, ln_g, ln_b, alpha, ws, out);
    }
}

// Round 7
// 1071.665 us; speedup vs baseline: 1.0600x; 1.0480x over previous
//
#include <hip/hip_runtime.h>
#include <math.h>

// TriDirectionalMamba: C=64, N=16, DI=128, K=4, DT_RANK=4, L=48, 48^3, B=1.
// v7 = v6 with the dir loops in k1_all/k3_all forced to runtime (#pragma
// unroll 1): v6 unrolled them 3x, tripling the live 64-reg weight arrays ->
// spill (k3_all WRITE_SIZE 248 MB vs 28 MB useful). Weights reload per dir
// iteration from L2 instead.
//   prep_big: ipTg = g(.)*in_proj^T (LN gamma folded), S1/S2 fold vectors.
//   k1_all:   stage x tile once, LN stats once, 3 folded GEMMs -> tb[dir]
//   k2_all:   grid 6912, dir = bid/2304; per-seq conv+x_proj+scan
//   k3_all:   stage x once, stats once, 3x(res GEMM+gate+out_proj) weighted
//             accumulate in LDS, single pure write of out (no RMW).
// Needs 3 tb buffers (170.2 MB). Fallback: v5 per-dir path (proven, 114 MB).

#define CS   110592                        // channel stride in x
#define TBF  (110592 * 128)                // one tb buffer, floats

// ---- big-path ws layout (floats) ----
#define IPTG_OFF (3 * TBF)
#define S1_OFF   (IPTG_OFF + 3 * 64 * 256)
#define S2_OFF   (S1_OFF + 3 * 256)
#define OPTB_OFF (S2_OFF + 3 * 256)
#define WS_BIG   (OPTB_OFF + 3 * 128 * 64)

// ---- small-path (v5) ws layout (floats) ----
#define IPT_OFF  TBF
#define OPT_OFF  (IPT_OFF + 3 * 64 * 256)
#define WS_SMALL (OPT_OFF + 3 * 128 * 64)

__device__ __forceinline__ float fast_silu(float x) {
    return x / (1.0f + __expf(-x));
}
// branchless stable softplus: max(x,0) + log(1+exp(-|x|))
__device__ __forceinline__ float softplus_f(float x) {
    float em = __expf(-fabsf(x));
    return fmaxf(x, 0.f) + __logf(1.f + em);
}

// ============================ BIG PATH =====================================

__global__ void prep_big(const float* __restrict__ ip,
                         const float* __restrict__ op,
                         const float* __restrict__ ln_g,
                         float* __restrict__ ws)
{
    float* ipTg = ws + IPTG_OFF;   // [dir][c][256], gamma folded
    float* opT  = ws + OPTB_OFF;   // [dir][dch][64]
    int i = blockIdx.x * 256 + threadIdx.x;
    if (i < 3 * 256 * 64) {
        int dir = i / 16384, r = i % 16384, j = r / 64, c = r % 64;
        ipTg[dir * 16384 + c * 256 + j] = ip[i] * ln_g[dir * 64 + c];
    } else {
        int k = i - 3 * 256 * 64;
        if (k < 3 * 64 * 128) {
            int dir = k / 8192, r = k % 8192, c = r / 128, dch = r % 128;
            opT[dir * 8192 + dch * 64 + c] = op[k];
        }
    }
}

// S1[dir][j] = sum_c g_c W[j][c] ; S2[dir][j] = sum_c b_c W[j][c]
__global__ void prep_s12(const float* __restrict__ ip,
                         const float* __restrict__ ln_g,
                         const float* __restrict__ ln_b,
                         float* __restrict__ ws)
{
    const int dir = blockIdx.x, j = threadIdx.x;
    const float* W = ip + dir * 16384 + j * 64;
    float s1 = 0.f, s2 = 0.f;
#pragma unroll 8
    for (int c = 0; c < 64; c++) {
        s1 += ln_g[dir * 64 + c] * W[c];
        s2 += ln_b[dir * 64 + c] * W[c];
    }
    ws[S1_OFF + dir * 256 + j] = s1;
    ws[S2_OFF + dir * 256 + j] = s2;
}

// --------------------------------------------------------------- k1_all ----
// Block = 64 consecutive output tokens, 256 threads. Stage raw x once,
// LN stats once, 3 folded GEMMs -> tb[dir][p][128] (xin halves only).
// dir loop is RUNTIME (unroll 1): one wgt[64] live at a time, no spill.
__global__ __launch_bounds__(256, 4)
void k1_all(const float* __restrict__ x, float* __restrict__ ws)
{
    __shared__ float Xs[64 * 64];    // [c][tok] raw
    __shared__ float ms[64], rss[64];
    const int tid = threadIdx.x;
    const int p0 = blockIdx.x * 64;

    {
        const int c0 = tid >> 6, j = tid & 63;
#pragma unroll
        for (int cc = 0; cc < 16; cc++) {
            int c = cc * 4 + c0;
            Xs[c * 64 + j] = x[c * CS + p0 + j];
        }
    }
    __syncthreads();

    if (tid < 64) {
        float s1 = 0.f, s2 = 0.f;
#pragma unroll
        for (int c = 0; c < 64; c++) {
            float v = Xs[c * 64 + tid];
            s1 += v; s2 += v * v;
        }
        float m = s1 * (1.f / 64.f);
        ms[tid]  = m;
        rss[tid] = rsqrtf(s2 * (1.f / 64.f) - m * m + 1e-5f);
    }
    __syncthreads();

    const int ch = tid & 127, half = tid >> 7;
#pragma unroll 1
    for (int dir = 0; dir < 3; dir++) {
        const float* ipTg = ws + IPTG_OFF + dir * 16384;
        const float S1v = ws[S1_OFF + dir * 256 + ch];
        const float S2v = ws[S2_OFF + dir * 256 + ch];
        float* tb = ws + (size_t)dir * TBF;

        float wgt[64];
#pragma unroll
        for (int c = 0; c < 64; c++) wgt[c] = ipTg[c * 256 + ch];

#pragma unroll
        for (int gg = 0; gg < 2; gg++) {
            int g = half * 2 + gg;
            float acc[16];
#pragma unroll
            for (int i = 0; i < 16; i++) acc[i] = 0.f;
#pragma unroll 8
            for (int c = 0; c < 64; c++) {
                const float4* xr = (const float4*)&Xs[c * 64 + g * 16];
                float4 x0 = xr[0], x1 = xr[1], x2 = xr[2], x3 = xr[3];
                float wv = wgt[c];
                acc[0]  += x0.x * wv; acc[1]  += x0.y * wv;
                acc[2]  += x0.z * wv; acc[3]  += x0.w * wv;
                acc[4]  += x1.x * wv; acc[5]  += x1.y * wv;
                acc[6]  += x1.z * wv; acc[7]  += x1.w * wv;
                acc[8]  += x2.x * wv; acc[9]  += x2.y * wv;
                acc[10] += x2.z * wv; acc[11] += x2.w * wv;
                acc[12] += x3.x * wv; acc[13] += x3.y * wv;
                acc[14] += x3.z * wv; acc[15] += x3.w * wv;
            }
#pragma unroll
            for (int i = 0; i < 16; i++) {
                int tok = g * 16 + i;
                float val = rss[tok] * (acc[i] - ms[tok] * S1v) + S2v;
                tb[(size_t)(p0 + tok) * 128 + ch] = val;
            }
        }
    }
}

// --------------------------------------------------------------- k2_all ----
// Grid 6912 = 3 dirs x 2304 seqs; block = one sequence (128 thr).
__global__ __launch_bounds__(128, 2)
void k2_all(const float* __restrict__ conv_w,
            const float* __restrict__ conv_b,
            const float* __restrict__ x_proj,
            const float* __restrict__ dt_w,
            const float* __restrict__ dt_b,
            const float* __restrict__ A_log,
            const float* __restrict__ D_ssm,
            float* __restrict__ ws)
{
    __shared__ float u_s[48 * 128];
    __shared__ float xd_s[48 * 36];
    const int tid = threadIdx.x;
    const int bid = blockIdx.x;
    const int dir = bid / 2304;
    const int s   = bid - dir * 2304;
    float* tb = ws + (size_t)dir * TBF;

    int base, TS;
    if (dir == 0)      { base = s;                               TS = 2304; }
    else if (dir == 1) { base = (s / 48) * 2304 + (s % 48);      TS = 48;   }
    else               { base = (s / 48) * 2304 + (s % 48) * 48; TS = 1;    }

    // --- phase A: depthwise causal conv + silu (thread = d) ---
    {
        const int d = tid;
        float xin[48];
#pragma unroll
        for (int t = 0; t < 48; t++)
            xin[t] = tb[(size_t)(base + t * TS) * 128 + d];
        float4 cw = *(const float4*)(conv_w + dir * 512 + d * 4);
        float cb  = conv_b[dir * 128 + d];
#pragma unroll
        for (int t = 0; t < 48; t++) {
            float a0 = (t >= 3) ? xin[t-3] : 0.f;
            float a1 = (t >= 2) ? xin[t-2] : 0.f;
            float a2 = (t >= 1) ? xin[t-1] : 0.f;
            float v = cw.x * a0 + cw.y * a1 + cw.z * a2 + cw.w * xin[t] + cb;
            u_s[t * 128 + (((((d >> 2) ^ (t & 7))) << 2) | (d & 3))] = fast_silu(v);
        }
    }
    __syncthreads();

    // --- phase B: x_proj u(128)->x_dbl(36); lane=t, j split by wave ---
    {
        const int t  = tid & 63;
        const int wv = __builtin_amdgcn_readfirstlane(tid >> 6);
        const int tr = (t < 48) ? t : 47;
        const int sw = tr & 7;
        float acc[18];
#pragma unroll
        for (int j = 0; j < 18; j++) acc[j] = 0.f;
        const float* xpw = x_proj + dir * 36 * 128 + (wv * 18) * 128;
        const float4* urow = (const float4*)&u_s[tr * 128];
#pragma unroll
        for (int qc = 0; qc < 4; qc++) {
            float4 u4[8];
#pragma unroll
            for (int q = 0; q < 8; q++) u4[q] = urow[qc * 8 + (q ^ sw)];
#pragma unroll
            for (int j = 0; j < 18; j++) {
                const float4* wr = (const float4*)(xpw + j * 128 + qc * 32);
                float a0 = 0.f, a1 = 0.f, a2 = 0.f, a3 = 0.f;
#pragma unroll
                for (int q = 0; q < 8; q++) {
                    float4 w4 = wr[q];
                    a0 += u4[q].x * w4.x; a1 += u4[q].y * w4.y;
                    a2 += u4[q].z * w4.z; a3 += u4[q].w * w4.w;
                }
                acc[j] += (a0 + a1) + (a2 + a3);
            }
        }
        if (t < 48) {
#pragma unroll
            for (int j = 0; j < 18; j++) xd_s[t * 36 + wv * 18 + j] = acc[j];
        }
    }
    __syncthreads();

    // --- phase C: selective scan (thread = d) ---
    {
        const int d = tid;
        float A[16];
        {
            const float4* al = (const float4*)(A_log + dir * 2048 + d * 16);
#pragma unroll
            for (int q = 0; q < 4; q++) {
                float4 v = al[q];
                A[4*q+0] = -__expf(v.x); A[4*q+1] = -__expf(v.y);
                A[4*q+2] = -__expf(v.z); A[4*q+3] = -__expf(v.w);
            }
        }
        float4 dtw = *(const float4*)(dt_w + dir * 512 + d * 4);
        float dtbv = dt_b[dir * 128 + d];
        float dsv  = D_ssm[dir * 128 + d];
        float h[16];
#pragma unroll
        for (int n = 0; n < 16; n++) h[n] = 0.f;

        const int dsw_hi = d >> 2, dlo = d & 3;
        for (int tt = 0; tt < 48; tt++) {
            const float4* xr4 = (const float4*)&xd_s[tt * 36];
            float4 R0 = xr4[0];
            float uu = u_s[tt * 128 + (((dsw_hi ^ (tt & 7)) << 2) | dlo)];
            float dl = dtbv + dtw.x*R0.x + dtw.y*R0.y + dtw.z*R0.z + dtw.w*R0.w;
            float delta = softplus_f(dl);
            float du = delta * uu;
            float4 B0 = xr4[1], B1 = xr4[2], B2 = xr4[3], B3 = xr4[4];
            float4 C0 = xr4[5], C1 = xr4[6], C2 = xr4[7], C3 = xr4[8];
            float y0 = 0.f, y1 = 0.f, y2 = 0.f, y3 = 0.f;
#define HN(n, Bc, Cc, ya) { float e = __expf(delta * A[n]); \
            h[n] = e * h[n] + du * (Bc); ya += h[n] * (Cc); }
            HN(0,  B0.x, C0.x, y0) HN(1,  B0.y, C0.y, y1)
            HN(2,  B0.z, C0.z, y2) HN(3,  B0.w, C0.w, y3)
            HN(4,  B1.x, C1.x, y0) HN(5,  B1.y, C1.y, y1)
            HN(6,  B1.z, C1.z, y2) HN(7,  B1.w, C1.w, y3)
            HN(8,  B2.x, C2.x, y0) HN(9,  B2.y, C2.y, y1)
            HN(10, B2.z, C2.z, y2) HN(11, B2.w, C2.w, y3)
            HN(12, B3.x, C3.x, y0) HN(13, B3.y, C3.y, y1)
            HN(14, B3.z, C3.z, y2) HN(15, B3.w, C3.w, y3)
#undef HN
            tb[(size_t)(base + tt * TS) * 128 + d] =
                ((y0 + y1) + (y2 + y3)) + uu * dsv;
        }
    }
}

// --------------------------------------------------------------- k3_all ----
// Block = 48 consecutive output tokens (d_sp,h). Stage x once, stats once,
// 3x(res GEMM [folded LN] + gate + out_proj) weighted-accumulated in LDS,
// single pure write of out. dir loop RUNTIME (unroll 1): no spill.
__global__ __launch_bounds__(128, 3)
void k3_all(const float* __restrict__ x,
            const float* __restrict__ alpha,
            float* __restrict__ ws,
            float* __restrict__ out)
{
    __shared__ float xs[64 * 52];    // raw x tile [c][w]
    __shared__ float sb[48 * 132];   // gated z [w][d]
    __shared__ float outA[64 * 49];  // weighted out accumulator [c][w]
    __shared__ float ms[48], rss[48];
    const int tid = threadIdx.x;
    const int b = blockIdx.x;
    const int d_sp = b / 48;
    const int h = b - d_sp * 48;
    const int obase = d_sp * 2304 + h * 48;

    float a0 = alpha[0], a1 = alpha[1], a2 = alpha[2];
    float mx = fmaxf(a0, fmaxf(a1, a2));
    float e0 = __expf(a0 - mx), e1 = __expf(a1 - mx), e2 = __expf(a2 - mx);
    float esum = e0 + e1 + e2;
    float wv3[3] = { e0 / esum, e1 / esum, e2 / esum };

    for (int o = tid; o < 64 * 48; o += 128) {
        int c = o / 48, w = o - c * 48;
        xs[c * 52 + w] = x[c * CS + obase + w];
    }
    __syncthreads();

    if (tid < 48) {
        const int w = tid;
        float s1 = 0.f, s2 = 0.f;
#pragma unroll
        for (int c = 0; c < 64; c++) {
            float v = xs[c * 52 + w];
            s1 += v; s2 += v * v;
        }
        float m = s1 * (1.f / 64.f);
        ms[w]  = m;
        rss[w] = rsqrtf(s2 * (1.f / 64.f) - m * m + 1e-5f);
    }
    __syncthreads();

    const int cp = tid & 31;
    const int wg = tid >> 5;

#pragma unroll 1
    for (int dir = 0; dir < 3; dir++) {
        // --- res GEMM (folded LN) + gate (thread = d) ---
        {
            const int d = tid;
            const float* ipTg = ws + IPTG_OFF + dir * 16384;
            const float S1v = ws[S1_OFF + dir * 256 + 128 + d];
            const float S2v = ws[S2_OFF + dir * 256 + 128 + d];
            const float* tb = ws + (size_t)dir * TBF;
            float wgt2[64];
#pragma unroll
            for (int c = 0; c < 64; c++) wgt2[c] = ipTg[c * 256 + 128 + d];
#pragma unroll
            for (int wb = 0; wb < 4; wb++) {
                float acc[12];
#pragma unroll
                for (int i = 0; i < 12; i++) acc[i] = 0.f;
#pragma unroll 8
                for (int c = 0; c < 64; c++) {
                    const float4* xr = (const float4*)&xs[c * 52 + wb * 12];
                    float4 v0 = xr[0], v1 = xr[1], v2 = xr[2];
                    float wv = wgt2[c];
                    acc[0] += v0.x * wv; acc[1] += v0.y * wv;
                    acc[2] += v0.z * wv; acc[3] += v0.w * wv;
                    acc[4] += v1.x * wv; acc[5] += v1.y * wv;
                    acc[6] += v1.z * wv; acc[7] += v1.w * wv;
                    acc[8] += v2.x * wv; acc[9] += v2.y * wv;
                    acc[10] += v2.z * wv; acc[11] += v2.w * wv;
                }
#pragma unroll
                for (int i = 0; i < 12; i++) {
                    int w = wb * 12 + i;
                    float res = rss[w] * (acc[i] - ms[w] * S1v) + S2v;
                    float zv = tb[(size_t)(obase + w) * 128 + d];
                    sb[w * 132 + d] = zv * fast_silu(res);
                }
            }
        }
        __syncthreads();

        // --- out_proj, weighted accumulate into outA ---
        {
            const float* opT = ws + OPTB_OFF + dir * 8192;
            float acc0[12], acc1[12];
#pragma unroll
            for (int i = 0; i < 12; i++) { acc0[i] = 0.f; acc1[i] = 0.f; }
#pragma unroll 2
            for (int dc = 0; dc < 32; dc++) {
                float w0[4], w1[4];
#pragma unroll
                for (int i = 0; i < 4; i++) {
                    w0[i] = opT[(dc * 4 + i) * 64 + cp];
                    w1[i] = opT[(dc * 4 + i) * 64 + cp + 32];
                }
#pragma unroll
                for (int i = 0; i < 12; i++) {
                    int w = wg * 12 + i;
                    float4 z4 = *(const float4*)&sb[w * 132 + dc * 4];
                    acc0[i] += z4.x * w0[0] + z4.y * w0[1] + z4.z * w0[2] + z4.w * w0[3];
                    acc1[i] += z4.x * w1[0] + z4.y * w1[1] + z4.z * w1[2] + z4.w * w1[3];
                }
            }
            float wd = wv3[dir];
            if (dir == 0) {
#pragma unroll
                for (int i = 0; i < 12; i++) {
                    int w = wg * 12 + i;
                    outA[cp * 49 + w]        = wd * acc0[i];
                    outA[(cp + 32) * 49 + w] = wd * acc1[i];
                }
            } else {
#pragma unroll
                for (int i = 0; i < 12; i++) {
                    int w = wg * 12 + i;
                    outA[cp * 49 + w]        += wd * acc0[i];
                    outA[(cp + 32) * 49 + w] += wd * acc1[i];
                }
            }
        }
        __syncthreads();   // sb reuse next dir; outA complete after last dir
    }

    for (int o = tid; o < 3072; o += 128) {
        int c = o / 48, w = o - c * 48;
        out[c * CS + obase + w] = outA[c * 49 + w];
    }
}

// ====================== SMALL PATH (v5, proven) ============================

__global__ void prep_kernel(const float* __restrict__ ip,
                            const float* __restrict__ op,
                            float* __restrict__ ws)
{
    float* ipT = ws + IPT_OFF;
    float* opT = ws + OPT_OFF;
    int i = blockIdx.x * 256 + threadIdx.x;
    if (i < 3 * 256 * 64) {
        int dir = i / 16384, r = i % 16384, j = r / 64, c = r % 64;
        ipT[dir * 16384 + c * 256 + j] = ip[i];
    } else {
        int k = i - 3 * 256 * 64;
        if (k < 3 * 64 * 128) {
            int dir = k / 8192, r = k % 8192, c = r / 128, dch = r % 128;
            opT[dir * 8192 + dch * 64 + c] = op[k];
        }
    }
}

template<int DIR>
__global__ __launch_bounds__(256, 4)
void k1_lnproj(const float* __restrict__ x,
               const float* __restrict__ ln_g,
               const float* __restrict__ ln_b,
               float* __restrict__ ws)
{
    __shared__ float Xs[64 * 64];
    const float* ipT = ws + IPT_OFF + DIR * 16384;
    float* tb = ws;
    const int tid = threadIdx.x;
    const int p0 = blockIdx.x * 64;
    {
        const int c0 = tid >> 6, j = tid & 63;
#pragma unroll
        for (int cc = 0; cc < 16; cc++) {
            int c = cc * 4 + c0;
            Xs[c * 64 + j] = x[c * CS + p0 + j];
        }
    }
    __syncthreads();
    if (tid < 64) {
        float s1 = 0.f, s2 = 0.f;
#pragma unroll
        for (int c = 0; c < 64; c++) {
            float v = Xs[c * 64 + tid];
            s1 += v; s2 += v * v;
        }
        float m  = s1 * (1.f / 64.f);
        float rs = rsqrtf(s2 * (1.f / 64.f) - m * m + 1e-5f);
#pragma unroll
        for (int c = 0; c < 64; c++) {
            Xs[c * 64 + tid] = (Xs[c * 64 + tid] - m) * rs * ln_g[DIR * 64 + c]
                               + ln_b[DIR * 64 + c];
        }
    }
    __syncthreads();
    const int ch = tid & 127, half = tid >> 7;
    float wgt[64];
#pragma unroll
    for (int c = 0; c < 64; c++) wgt[c] = ipT[c * 256 + ch];
#pragma unroll
    for (int gg = 0; gg < 2; gg++) {
        int g = half * 2 + gg;
        float acc[16];
#pragma unroll
        for (int i = 0; i < 16; i++) acc[i] = 0.f;
#pragma unroll 8
        for (int c = 0; c < 64; c++) {
            const float4* xr = (const float4*)&Xs[c * 64 + g * 16];
            float4 x0 = xr[0], x1 = xr[1], x2 = xr[2], x3 = xr[3];
            float wv = wgt[c];
            acc[0]  += x0.x * wv; acc[1]  += x0.y * wv;
            acc[2]  += x0.z * wv; acc[3]  += x0.w * wv;
            acc[4]  += x1.x * wv; acc[5]  += x1.y * wv;
            acc[6]  += x1.z * wv; acc[7]  += x1.w * wv;
            acc[8]  += x2.x * wv; acc[9]  += x2.y * wv;
            acc[10] += x2.z * wv; acc[11] += x2.w * wv;
            acc[12] += x3.x * wv; acc[13] += x3.y * wv;
            acc[14] += x3.z * wv; acc[15] += x3.w * wv;
        }
#pragma unroll
        for (int i = 0; i < 16; i++)
            tb[(size_t)(p0 + g * 16 + i) * 128 + ch] = acc[i];
    }
}

template<int DIR>
__global__ __launch_bounds__(128, 2)
void k2_scan(const float* __restrict__ conv_w,
             const float* __restrict__ conv_b,
             const float* __restrict__ x_proj,
             const float* __restrict__ dt_w,
             const float* __restrict__ dt_b,
             const float* __restrict__ A_log,
             const float* __restrict__ D_ssm,
             float* __restrict__ ws)
{
    __shared__ float u_s[48 * 128];
    __shared__ float xd_s[48 * 36];
    float* tb = ws;
    const int tid = threadIdx.x;
    const int s = blockIdx.x;
    int base, TS;
    if (DIR == 0)      { base = s;                               TS = 2304; }
    else if (DIR == 1) { base = (s / 48) * 2304 + (s % 48);      TS = 48;   }
    else               { base = (s / 48) * 2304 + (s % 48) * 48; TS = 1;    }
    {
        const int d = tid;
        float xin[48];
#pragma unroll
        for (int t = 0; t < 48; t++)
            xin[t] = tb[(size_t)(base + t * TS) * 128 + d];
        float4 cw = *(const float4*)(conv_w + DIR * 512 + d * 4);
        float cb  = conv_b[DIR * 128 + d];
#pragma unroll
        for (int t = 0; t < 48; t++) {
            float a0 = (t >= 3) ? xin[t-3] : 0.f;
            float a1 = (t >= 2) ? xin[t-2] : 0.f;
            float a2 = (t >= 1) ? xin[t-1] : 0.f;
            float v = cw.x * a0 + cw.y * a1 + cw.z * a2 + cw.w * xin[t] + cb;
            u_s[t * 128 + (((((d >> 2) ^ (t & 7))) << 2) | (d & 3))] = fast_silu(v);
        }
    }
    __syncthreads();
    {
        const int t  = tid & 63;
        const int wv = __builtin_amdgcn_readfirstlane(tid >> 6);
        const int tr = (t < 48) ? t : 47;
        const int sw = tr & 7;
        float acc[18];
#pragma unroll
        for (int j = 0; j < 18; j++) acc[j] = 0.f;
        const float* xpw = x_proj + DIR * 36 * 128 + (wv * 18) * 128;
        const float4* urow = (const float4*)&u_s[tr * 128];
#pragma unroll
        for (int qc = 0; qc < 4; qc++) {
            float4 u4[8];
#pragma unroll
            for (int q = 0; q < 8; q++) u4[q] = urow[qc * 8 + (q ^ sw)];
#pragma unroll
            for (int j = 0; j < 18; j++) {
                const float4* wr = (const float4*)(xpw + j * 128 + qc * 32);
                float a0 = 0.f, a1 = 0.f, a2 = 0.f, a3 = 0.f;
#pragma unroll
                for (int q = 0; q < 8; q++) {
                    float4 w4 = wr[q];
                    a0 += u4[q].x * w4.x; a1 += u4[q].y * w4.y;
                    a2 += u4[q].z * w4.z; a3 += u4[q].w * w4.w;
                }
                acc[j] += (a0 + a1) + (a2 + a3);
            }
        }
        if (t < 48) {
#pragma unroll
            for (int j = 0; j < 18; j++) xd_s[t * 36 + wv * 18 + j] = acc[j];
        }
    }
    __syncthreads();
    {
        const int d = tid;
        float A[16];
        {
            const float4* al = (const float4*)(A_log + DIR * 2048 + d * 16);
#pragma unroll
            for (int q = 0; q < 4; q++) {
                float4 v = al[q];
                A[4*q+0] = -__expf(v.x); A[4*q+1] = -__expf(v.y);
                A[4*q+2] = -__expf(v.z); A[4*q+3] = -__expf(v.w);
            }
        }
        float4 dtw = *(const float4*)(dt_w + DIR * 512 + d * 4);
        float dtbv = dt_b[DIR * 128 + d];
        float dsv  = D_ssm[DIR * 128 + d];
        float h[16];
#pragma unroll
        for (int n = 0; n < 16; n++) h[n] = 0.f;
        const int dsw_hi = d >> 2, dlo = d & 3;
        for (int tt = 0; tt < 48; tt++) {
            const float4* xr4 = (const float4*)&xd_s[tt * 36];
            float4 R0 = xr4[0];
            float uu = u_s[tt * 128 + (((dsw_hi ^ (tt & 7)) << 2) | dlo)];
            float dl = dtbv + dtw.x*R0.x + dtw.y*R0.y + dtw.z*R0.z + dtw.w*R0.w;
            float delta = softplus_f(dl);
            float du = delta * uu;
            float4 B0 = xr4[1], B1 = xr4[2], B2 = xr4[3], B3 = xr4[4];
            float4 C0 = xr4[5], C1 = xr4[6], C2 = xr4[7], C3 = xr4[8];
            float y0 = 0.f, y1 = 0.f, y2 = 0.f, y3 = 0.f;
#define HN(n, Bc, Cc, ya) { float e = __expf(delta * A[n]); \
            h[n] = e * h[n] + du * (Bc); ya += h[n] * (Cc); }
            HN(0,  B0.x, C0.x, y0) HN(1,  B0.y, C0.y, y1)
            HN(2,  B0.z, C0.z, y2) HN(3,  B0.w, C0.w, y3)
            HN(4,  B1.x, C1.x, y0) HN(5,  B1.y, C1.y, y1)
            HN(6,  B1.z, C1.z, y2) HN(7,  B1.w, C1.w, y3)
            HN(8,  B2.x, C2.x, y0) HN(9,  B2.y, C2.y, y1)
            HN(10, B2.z, C2.z, y2) HN(11, B2.w, C2.w, y3)
            HN(12, B3.x, C3.x, y0) HN(13, B3.y, C3.y, y1)
            HN(14, B3.z, C3.z, y2) HN(15, B3.w, C3.w, y3)
#undef HN
            tb[(size_t)(base + tt * TS) * 128 + d] =
                ((y0 + y1) + (y2 + y3)) + uu * dsv;
        }
    }
}

template<int DIR, bool FIRST>
__global__ __launch_bounds__(128, 4)
void k3_outproj(const float* __restrict__ x,
                const float* __restrict__ ln_g,
                const float* __restrict__ ln_b,
                const float* __restrict__ alpha,
                float* __restrict__ ws,
                float* __restrict__ out)
{
    __shared__ float sb[48 * 132];
    __shared__ float xs[64 * 52];
    float* tb = ws;
    const float* ipT = ws + IPT_OFF + DIR * 16384;
    const float* opT = ws + OPT_OFF + DIR * 8192;
    const int tid = threadIdx.x;
    const int b = blockIdx.x;
    const int d_sp = b / 48;
    const int h = b - d_sp * 48;
    const int obase = d_sp * 2304 + h * 48;
    float a0 = alpha[0], a1 = alpha[1], a2 = alpha[2];
    float mx = fmaxf(a0, fmaxf(a1, a2));
    float e0 = __expf(a0 - mx), e1 = __expf(a1 - mx), e2 = __expf(a2 - mx);
    float wdir = ((DIR == 0) ? e0 : (DIR == 1) ? e1 : e2) / (e0 + e1 + e2);
    for (int o = tid; o < 64 * 48; o += 128) {
        int c = o / 48, w = o - c * 48;
        xs[c * 52 + w] = x[c * CS + obase + w];
    }
    __syncthreads();
    if (tid < 48) {
        const int w = tid;
        float s1 = 0.f, s2 = 0.f;
#pragma unroll
        for (int c = 0; c < 64; c++) {
            float v = xs[c * 52 + w];
            s1 += v; s2 += v * v;
        }
        float m  = s1 * (1.f / 64.f);
        float rs = rsqrtf(s2 * (1.f / 64.f) - m * m + 1e-5f);
#pragma unroll
        for (int c = 0; c < 64; c++) {
            xs[c * 52 + w] = (xs[c * 52 + w] - m) * rs * ln_g[DIR * 64 + c]
                             + ln_b[DIR * 64 + c];
        }
    }
    __syncthreads();
    {
        const int d = tid;
        float wgt2[64];
#pragma unroll
        for (int c = 0; c < 64; c++) wgt2[c] = ipT[c * 256 + 128 + d];
#pragma unroll
        for (int wb = 0; wb < 4; wb++) {
            float acc[12];
#pragma unroll
            for (int i = 0; i < 12; i++) acc[i] = 0.f;
#pragma unroll 8
            for (int c = 0; c < 64; c++) {
                const float4* xr = (const float4*)&xs[c * 52 + wb * 12];
                float4 v0 = xr[0], v1 = xr[1], v2 = xr[2];
                float wv = wgt2[c];
                acc[0] += v0.x * wv; acc[1] += v0.y * wv;
                acc[2] += v0.z * wv; acc[3] += v0.w * wv;
                acc[4] += v1.x * wv; acc[5] += v1.y * wv;
                acc[6] += v1.z * wv; acc[7] += v1.w * wv;
                acc[8] += v2.x * wv; acc[9] += v2.y * wv;
                acc[10] += v2.z * wv; acc[11] += v2.w * wv;
            }
#pragma unroll
            for (int i = 0; i < 12; i++) {
                int w = wb * 12 + i;
                float zv = tb[(size_t)(obase + w) * 128 + d];
                sb[w * 132 + d] = zv * fast_silu(acc[i]);
            }
        }
    }
    __syncthreads();
    const int cp = tid & 31;
    const int wg = tid >> 5;
    float acc0[12], acc1[12];
#pragma unroll
    for (int i = 0; i < 12; i++) { acc0[i] = 0.f; acc1[i] = 0.f; }
#pragma unroll 2
    for (int dc = 0; dc < 32; dc++) {
        float w0[4], w1[4];
#pragma unroll
        for (int i = 0; i < 4; i++) {
            w0[i] = opT[(dc * 4 + i) * 64 + cp];
            w1[i] = opT[(dc * 4 + i) * 64 + cp + 32];
        }
#pragma unroll
        for (int i = 0; i < 12; i++) {
            int w = wg * 12 + i;
            float4 z4 = *(const float4*)&sb[w * 132 + dc * 4];
            acc0[i] += z4.x * w0[0] + z4.y * w0[1] + z4.z * w0[2] + z4.w * w0[3];
            acc1[i] += z4.x * w1[0] + z4.y * w1[1] + z4.z * w1[2] + z4.w * w1[3];
        }
    }
    __syncthreads();
#pragma unroll
    for (int i = 0; i < 12; i++) {
        int w = wg * 12 + i;
        sb[cp * 49 + w]        = acc0[i];
        sb[(cp + 32) * 49 + w] = acc1[i];
    }
    __syncthreads();
    for (int o = tid; o < 3072; o += 128) {
        int c = o / 48, w = o - c * 48;
        int addr = c * CS + obase + w;
        float val = wdir * sb[c * 49 + w];
        if (!FIRST) val += out[addr];
        out[addr] = val;
    }
}

// ------------------------------------------------------------- launch -----
extern "C" void kernel_launch(void* const* d_in, const int* in_sizes, int n_in,
                              void* d_out, int out_size, void* d_ws, size_t ws_size,
                              hipStream_t stream) {
    const float* x        = (const float*)d_in[0];
    const float* in_proj  = (const float*)d_in[1];
    const float* conv_w   = (const float*)d_in[2];
    const float* conv_b   = (const float*)d_in[3];
    const float* x_proj   = (const float*)d_in[4];
    const float* dt_w     = (const float*)d_in[5];
    const float* dt_b     = (const float*)d_in[6];
    const float* A_log    = (const float*)d_in[7];
    const float* D_ssm    = (const float*)d_in[8];
    const float* out_proj = (const float*)d_in[9];
    const float* ln_g     = (const float*)d_in[10];
    const float* ln_b     = (const float*)d_in[11];
    const float* alpha    = (const float*)d_in[12];
    float* out = (float*)d_out;
    float* ws  = (float*)d_ws;

    if (ws_size >= (size_t)WS_BIG * 4) {
        prep_big<<<288, 256, 0, stream>>>(in_proj, out_proj, ln_g, ws);
        prep_s12<<<3, 256, 0, stream>>>(in_proj, ln_g, ln_b, ws);
        k1_all<<<1728, 256, 0, stream>>>(x, ws);
        k2_all<<<6912, 128, 0, stream>>>(conv_w, conv_b, x_proj, dt_w, dt_b,
                                         A_log, D_ssm, ws);
        k3_all<<<2304, 128, 0, stream>>>(x, alpha, ws, out);
    } else {
        prep_kernel<<<288, 256, 0, stream>>>(in_proj, out_proj, ws);

        k1_lnproj<0><<<1728, 256, 0, stream>>>(x, ln_g, ln_b, ws);
        k2_scan<0><<<2304, 128, 0, stream>>>(conv_w, conv_b, x_proj, dt_w, dt_b, A_log, D_ssm, ws);
        k3_outproj<0, true ><<<2304, 128, 0, stream>>>(x, ln_g, ln_b, alpha, ws, out);

        k1_lnproj<1><<<1728, 256, 0, stream>>>(x, ln_g, ln_b, ws);
        k2_scan<1><<<2304, 128, 0, stream>>>(conv_w, conv_b, x_proj, dt_w, dt_b, A_log, D_ssm, ws);
        k3_outproj<1, false><<<2304, 128, 0, stream>>>(x, ln_g, ln_b, alpha, ws, out);

        k1_lnproj<2><<<1728, 256, 0, stream>>>(x, ln_g, ln_b, ws);
        k2_scan<2><<<2304, 128, 0, stream>>>(conv_w, conv_b, x_proj, dt_w, dt_b, A_log, D_ssm, ws);
        k3_outproj<2, false><<<2304, 128, 0, stream>>>(x, ln_g, ln_b, alpha, ws, out);
    }
}

// Round 8
// 1017.518 us; speedup vs baseline: 1.1165x; 1.0532x over previous
//
#include <hip/hip_runtime.h>
#include <math.h>

// TriDirectionalMamba: C=64, N=16, DI=128, K=4, DT_RANK=4, L=48, 48^3, B=1.
// v8: big-ws merged pipeline.
//   k1_all: stage x tile once, LN stats once, 3 folded GEMMs -> tb[dir]
//   k2_all: grid 6912 per-seq conv+x_proj+scan; scan decay via POW-LADDER
//           (A[n] == -(n+1) guarded by __all) -> 3 trans/step instead of 18.
//   k3_all: 256 thr / 64 linear tokens; res GEMM thread=(half,d); out_proj
//           thread=(c,grp) with weighted accumulator in REGISTERS across the
//           dir loop; single transpose; pure coalesced out write.
// Needs 3 tb buffers (170.2 MB). Fallback: v5 per-dir path (proven, 114 MB).

#define CS   110592                        // channel stride in x
#define TBF  (110592 * 128)                // one tb buffer, floats

// ---- big-path ws layout (floats) ----
#define IPTG_OFF (3 * TBF)
#define S1_OFF   (IPTG_OFF + 3 * 64 * 256)
#define S2_OFF   (S1_OFF + 3 * 256)
#define OPTB_OFF (S2_OFF + 3 * 256)
#define WS_BIG   (OPTB_OFF + 3 * 128 * 64)

// ---- small-path (v5) ws layout (floats) ----
#define IPT_OFF  TBF
#define OPT_OFF  (IPT_OFF + 3 * 64 * 256)
#define WS_SMALL (OPT_OFF + 3 * 128 * 64)

__device__ __forceinline__ float fast_silu(float x) {
    return x / (1.0f + __expf(-x));
}
// branchless stable softplus: max(x,0) + log(1+exp(-|x|))
__device__ __forceinline__ float softplus_f(float x) {
    float em = __expf(-fabsf(x));
    return fmaxf(x, 0.f) + __logf(1.f + em);
}

// ============================ BIG PATH =====================================

__global__ void prep_big(const float* __restrict__ ip,
                         const float* __restrict__ op,
                         const float* __restrict__ ln_g,
                         float* __restrict__ ws)
{
    float* ipTg = ws + IPTG_OFF;   // [dir][c][256], gamma folded
    float* opT  = ws + OPTB_OFF;   // [dir][dch][64]
    int i = blockIdx.x * 256 + threadIdx.x;
    if (i < 3 * 256 * 64) {
        int dir = i / 16384, r = i % 16384, j = r / 64, c = r % 64;
        ipTg[dir * 16384 + c * 256 + j] = ip[i] * ln_g[dir * 64 + c];
    } else {
        int k = i - 3 * 256 * 64;
        if (k < 3 * 64 * 128) {
            int dir = k / 8192, r = k % 8192, c = r / 128, dch = r % 128;
            opT[dir * 8192 + dch * 64 + c] = op[k];
        }
    }
}

// S1[dir][j] = sum_c g_c W[j][c] ; S2[dir][j] = sum_c b_c W[j][c]
__global__ void prep_s12(const float* __restrict__ ip,
                         const float* __restrict__ ln_g,
                         const float* __restrict__ ln_b,
                         float* __restrict__ ws)
{
    const int dir = blockIdx.x, j = threadIdx.x;
    const float* W = ip + dir * 16384 + j * 64;
    float s1 = 0.f, s2 = 0.f;
#pragma unroll 8
    for (int c = 0; c < 64; c++) {
        s1 += ln_g[dir * 64 + c] * W[c];
        s2 += ln_b[dir * 64 + c] * W[c];
    }
    ws[S1_OFF + dir * 256 + j] = s1;
    ws[S2_OFF + dir * 256 + j] = s2;
}

// --------------------------------------------------------------- k1_all ----
__global__ __launch_bounds__(256, 4)
void k1_all(const float* __restrict__ x, float* __restrict__ ws)
{
    __shared__ float Xs[64 * 64];    // [c][tok] raw
    __shared__ float ms[64], rss[64];
    const int tid = threadIdx.x;
    const int p0 = blockIdx.x * 64;

    {
        const int c0 = tid >> 6, j = tid & 63;
#pragma unroll
        for (int cc = 0; cc < 16; cc++) {
            int c = cc * 4 + c0;
            Xs[c * 64 + j] = x[c * CS + p0 + j];
        }
    }
    __syncthreads();

    if (tid < 64) {
        float s1 = 0.f, s2 = 0.f;
#pragma unroll
        for (int c = 0; c < 64; c++) {
            float v = Xs[c * 64 + tid];
            s1 += v; s2 += v * v;
        }
        float m = s1 * (1.f / 64.f);
        ms[tid]  = m;
        rss[tid] = rsqrtf(s2 * (1.f / 64.f) - m * m + 1e-5f);
    }
    __syncthreads();

    const int ch = tid & 127, half = tid >> 7;
#pragma unroll 1
    for (int dir = 0; dir < 3; dir++) {
        const float* ipTg = ws + IPTG_OFF + dir * 16384;
        const float S1v = ws[S1_OFF + dir * 256 + ch];
        const float S2v = ws[S2_OFF + dir * 256 + ch];
        float* tb = ws + (size_t)dir * TBF;

        float wgt[64];
#pragma unroll
        for (int c = 0; c < 64; c++) wgt[c] = ipTg[c * 256 + ch];

#pragma unroll
        for (int gg = 0; gg < 2; gg++) {
            int g = half * 2 + gg;
            float acc[16];
#pragma unroll
            for (int i = 0; i < 16; i++) acc[i] = 0.f;
#pragma unroll 8
            for (int c = 0; c < 64; c++) {
                const float4* xr = (const float4*)&Xs[c * 64 + g * 16];
                float4 x0 = xr[0], x1 = xr[1], x2 = xr[2], x3 = xr[3];
                float wv = wgt[c];
                acc[0]  += x0.x * wv; acc[1]  += x0.y * wv;
                acc[2]  += x0.z * wv; acc[3]  += x0.w * wv;
                acc[4]  += x1.x * wv; acc[5]  += x1.y * wv;
                acc[6]  += x1.z * wv; acc[7]  += x1.w * wv;
                acc[8]  += x2.x * wv; acc[9]  += x2.y * wv;
                acc[10] += x2.z * wv; acc[11] += x2.w * wv;
                acc[12] += x3.x * wv; acc[13] += x3.y * wv;
                acc[14] += x3.z * wv; acc[15] += x3.w * wv;
            }
#pragma unroll
            for (int i = 0; i < 16; i++) {
                int tok = g * 16 + i;
                float val = rss[tok] * (acc[i] - ms[tok] * S1v) + S2v;
                tb[(size_t)(p0 + tok) * 128 + ch] = val;
            }
        }
    }
}

// --------------------------------------------------------------- k2_all ----
// Grid 6912 = 3 dirs x 2304 seqs; block = one sequence (128 thr).
// Scan decay via pow-ladder when A[n] == -(n+1) (always true for this model;
// guarded by __all, generic 16-exp fallback otherwise).
__global__ __launch_bounds__(128, 2)
void k2_all(const float* __restrict__ conv_w,
            const float* __restrict__ conv_b,
            const float* __restrict__ x_proj,
            const float* __restrict__ dt_w,
            const float* __restrict__ dt_b,
            const float* __restrict__ A_log,
            const float* __restrict__ D_ssm,
            float* __restrict__ ws)
{
    __shared__ float u_s[48 * 128];
    __shared__ float xd_s[48 * 36];
    const int tid = threadIdx.x;
    const int bid = blockIdx.x;
    const int dir = bid / 2304;
    const int s   = bid - dir * 2304;
    float* tb = ws + (size_t)dir * TBF;

    int base, TS;
    if (dir == 0)      { base = s;                               TS = 2304; }
    else if (dir == 1) { base = (s / 48) * 2304 + (s % 48);      TS = 48;   }
    else               { base = (s / 48) * 2304 + (s % 48) * 48; TS = 1;    }

    // --- phase A: depthwise causal conv + silu (thread = d) ---
    {
        const int d = tid;
        float xin[48];
#pragma unroll
        for (int t = 0; t < 48; t++)
            xin[t] = tb[(size_t)(base + t * TS) * 128 + d];
        float4 cw = *(const float4*)(conv_w + dir * 512 + d * 4);
        float cb  = conv_b[dir * 128 + d];
#pragma unroll
        for (int t = 0; t < 48; t++) {
            float a0 = (t >= 3) ? xin[t-3] : 0.f;
            float a1 = (t >= 2) ? xin[t-2] : 0.f;
            float a2 = (t >= 1) ? xin[t-1] : 0.f;
            float v = cw.x * a0 + cw.y * a1 + cw.z * a2 + cw.w * xin[t] + cb;
            u_s[t * 128 + (((((d >> 2) ^ (t & 7))) << 2) | (d & 3))] = fast_silu(v);
        }
    }
    __syncthreads();

    // --- phase B: x_proj u(128)->x_dbl(36); lane=t, j split by wave ---
    {
        const int t  = tid & 63;
        const int wv = __builtin_amdgcn_readfirstlane(tid >> 6);
        const int tr = (t < 48) ? t : 47;
        const int sw = tr & 7;
        float acc[18];
#pragma unroll
        for (int j = 0; j < 18; j++) acc[j] = 0.f;
        const float* xpw = x_proj + dir * 36 * 128 + (wv * 18) * 128;
        const float4* urow = (const float4*)&u_s[tr * 128];
#pragma unroll
        for (int qc = 0; qc < 4; qc++) {
            float4 u4[8];
#pragma unroll
            for (int q = 0; q < 8; q++) u4[q] = urow[qc * 8 + (q ^ sw)];
#pragma unroll
            for (int j = 0; j < 18; j++) {
                const float4* wr = (const float4*)(xpw + j * 128 + qc * 32);
                float a0 = 0.f, a1 = 0.f, a2 = 0.f, a3 = 0.f;
#pragma unroll
                for (int q = 0; q < 8; q++) {
                    float4 w4 = wr[q];
                    a0 += u4[q].x * w4.x; a1 += u4[q].y * w4.y;
                    a2 += u4[q].z * w4.z; a3 += u4[q].w * w4.w;
                }
                acc[j] += (a0 + a1) + (a2 + a3);
            }
        }
        if (t < 48) {
#pragma unroll
            for (int j = 0; j < 18; j++) xd_s[t * 36 + wv * 18 + j] = acc[j];
        }
    }
    __syncthreads();

    // --- phase C: selective scan (thread = d) ---
    {
        const int d = tid;
        float A[16];
        bool pk = true;
        {
            const float4* al = (const float4*)(A_log + dir * 2048 + d * 16);
#pragma unroll
            for (int q = 0; q < 4; q++) {
                float4 v = al[q];
                A[4*q+0] = -__expf(v.x); A[4*q+1] = -__expf(v.y);
                A[4*q+2] = -__expf(v.z); A[4*q+3] = -__expf(v.w);
            }
#pragma unroll
            for (int n = 0; n < 16; n++)
                pk = pk && (fabsf(A[n] + (float)(n + 1)) < 1e-3f);
        }
        const int pok = __all(pk ? 1 : 0);
        float4 dtw = *(const float4*)(dt_w + dir * 512 + d * 4);
        float dtbv = dt_b[dir * 128 + d];
        float dsv  = D_ssm[dir * 128 + d];
        float h[16];
#pragma unroll
        for (int n = 0; n < 16; n++) h[n] = 0.f;

        const int dsw_hi = d >> 2, dlo = d & 3;
        for (int tt = 0; tt < 48; tt++) {
            const float4* xr4 = (const float4*)&xd_s[tt * 36];
            float4 R0 = xr4[0];
            float uu = u_s[tt * 128 + (((dsw_hi ^ (tt & 7)) << 2) | dlo)];
            float dl = dtbv + dtw.x*R0.x + dtw.y*R0.y + dtw.z*R0.z + dtw.w*R0.w;
            float delta = softplus_f(dl);
            float du = delta * uu;
            float e[16];
            if (pok) {
                // e[n] = p^(n+1), p = exp(-delta): 1 trans + 16 muls, depth 4
                float p  = __expf(-delta);
                float p2 = p * p, p3 = p2 * p, p4 = p2 * p2;
                e[0] = p;       e[1] = p2;      e[2] = p3;      e[3] = p4;
                float p8 = p4 * p4;
                e[4] = p4 * p;  e[5] = p4 * p2; e[6] = p4 * p3; e[7] = p8;
                float p12 = p8 * p4;
                e[8] = p8 * p;  e[9] = p8 * p2; e[10] = p8 * p3; e[11] = p12;
                e[12] = p12 * p; e[13] = p12 * p2; e[14] = p12 * p3; e[15] = p12 * p4;
            } else {
#pragma unroll
                for (int n = 0; n < 16; n++) e[n] = __expf(delta * A[n]);
            }
            float4 B0 = xr4[1], B1 = xr4[2], B2 = xr4[3], B3 = xr4[4];
            float4 C0 = xr4[5], C1 = xr4[6], C2 = xr4[7], C3 = xr4[8];
            float y0 = 0.f, y1 = 0.f, y2 = 0.f, y3 = 0.f;
#define HN(n, Bc, Cc, ya) { h[n] = e[n] * h[n] + du * (Bc); ya += h[n] * (Cc); }
            HN(0,  B0.x, C0.x, y0) HN(1,  B0.y, C0.y, y1)
            HN(2,  B0.z, C0.z, y2) HN(3,  B0.w, C0.w, y3)
            HN(4,  B1.x, C1.x, y0) HN(5,  B1.y, C1.y, y1)
            HN(6,  B1.z, C1.z, y2) HN(7,  B1.w, C1.w, y3)
            HN(8,  B2.x, C2.x, y0) HN(9,  B2.y, C2.y, y1)
            HN(10, B2.z, C2.z, y2) HN(11, B2.w, C2.w, y3)
            HN(12, B3.x, C3.x, y0) HN(13, B3.y, C3.y, y1)
            HN(14, B3.z, C3.z, y2) HN(15, B3.w, C3.w, y3)
#undef HN
            tb[(size_t)(base + tt * TS) * 128 + d] =
                ((y0 + y1) + (y2 + y3)) + uu * dsv;
        }
    }
}

// --------------------------------------------------------------- k3_all ----
// Block = 64 consecutive linear tokens p0..p0+63 (x/out/tb all linear in p),
// 256 threads. Stage x once, stats once; per dir: res GEMM thread=(half,d)
// -> gate -> sb; out_proj thread=(oc,grp) accumulating softmax(alpha)-weighted
// result in REGISTERS. One transpose + single pure coalesced out write.
__global__ __launch_bounds__(256, 3)
void k3_all(const float* __restrict__ x,
            const float* __restrict__ alpha,
            float* __restrict__ ws,
            float* __restrict__ out)
{
    __shared__ float xs[64 * 68];     // [c][tok] raw x, pad 68 (conflict-free)
    __shared__ float sb[64 * 132];    // gated z [tok][d]; reused outT[64][65]
    __shared__ float ms[64], rss[64];
    const int tid = threadIdx.x;
    const int p0 = blockIdx.x * 64;

    float a0 = alpha[0], a1 = alpha[1], a2 = alpha[2];
    float mx = fmaxf(a0, fmaxf(a1, a2));
    float ea0 = __expf(a0 - mx), ea1 = __expf(a1 - mx), ea2 = __expf(a2 - mx);
    float esum = ea0 + ea1 + ea2;

    // stage x tile (c-major, coalesced 256B per wave-load)
    {
        const int c0 = tid >> 6, j = tid & 63;
#pragma unroll
        for (int cc = 0; cc < 16; cc++) {
            int c = cc * 4 + c0;
            xs[c * 68 + j] = x[c * CS + p0 + j];
        }
    }
    __syncthreads();

    if (tid < 64) {
        float s1 = 0.f, s2 = 0.f;
#pragma unroll
        for (int c = 0; c < 64; c++) {
            float v = xs[c * 68 + tid];
            s1 += v; s2 += v * v;
        }
        float m = s1 * (1.f / 64.f);
        ms[tid]  = m;
        rss[tid] = rsqrtf(s2 * (1.f / 64.f) - m * m + 1e-5f);
    }
    __syncthreads();

    const int half = tid >> 7;          // token half (res phase)
    const int d    = tid & 127;         // res channel (res phase)
    const int oc   = tid & 63;          // out channel (out_proj phase)
    const int grp  = tid >> 6;          // token quarter of 16 (out_proj)

    float oacc[16];
#pragma unroll
    for (int i = 0; i < 16; i++) oacc[i] = 0.f;

#pragma unroll 1
    for (int dir = 0; dir < 3; dir++) {
        const float* ipTg = ws + IPTG_OFF + dir * 16384;
        const float* tbd  = ws + (size_t)dir * TBF;
        const float S1v = ws[S1_OFF + dir * 256 + 128 + d];
        const float S2v = ws[S2_OFF + dir * 256 + 128 + d];

        float wgt2[64];
#pragma unroll
        for (int c = 0; c < 64; c++) wgt2[c] = ipTg[c * 256 + 128 + d];

        // res GEMM (folded LN) + gate -> sb[tok][d]
#pragma unroll
        for (int sub = 0; sub < 2; sub++) {
            const int t0 = half * 32 + sub * 16;
            float acc[16];
#pragma unroll
            for (int i = 0; i < 16; i++) acc[i] = 0.f;
#pragma unroll 8
            for (int c = 0; c < 64; c++) {
                const float4* xr = (const float4*)&xs[c * 68 + t0];
                float4 v0 = xr[0], v1 = xr[1], v2 = xr[2], v3 = xr[3];
                float wv = wgt2[c];
                acc[0]  += v0.x * wv; acc[1]  += v0.y * wv;
                acc[2]  += v0.z * wv; acc[3]  += v0.w * wv;
                acc[4]  += v1.x * wv; acc[5]  += v1.y * wv;
                acc[6]  += v1.z * wv; acc[7]  += v1.w * wv;
                acc[8]  += v2.x * wv; acc[9]  += v2.y * wv;
                acc[10] += v2.z * wv; acc[11] += v2.w * wv;
                acc[12] += v3.x * wv; acc[13] += v3.y * wv;
                acc[14] += v3.z * wv; acc[15] += v3.w * wv;
            }
#pragma unroll
            for (int i = 0; i < 16; i++) {
                int tok = t0 + i;
                float res = rss[tok] * (acc[i] - ms[tok] * S1v) + S2v;
                float zv = tbd[(size_t)(p0 + tok) * 128 + d];
                sb[tok * 132 + d] = zv * fast_silu(res);
            }
        }
        __syncthreads();

        // out_proj partial, weighted accumulate into registers
        {
            const float* opT = ws + OPTB_OFF + dir * 8192;
            float wd = ((dir == 0) ? ea0 : (dir == 1) ? ea1 : ea2) / esum;
            float accL[16];
#pragma unroll
            for (int i = 0; i < 16; i++) accL[i] = 0.f;
#pragma unroll 2
            for (int dc = 0; dc < 32; dc++) {
                float w0[4];
#pragma unroll
                for (int q = 0; q < 4; q++)
                    w0[q] = opT[(dc * 4 + q) * 64 + oc];
#pragma unroll
                for (int i = 0; i < 16; i++) {
                    int tok = grp * 16 + i;
                    float4 z4 = *(const float4*)&sb[tok * 132 + dc * 4];
                    accL[i] += z4.x * w0[0] + z4.y * w0[1]
                             + z4.z * w0[2] + z4.w * w0[3];
                }
            }
#pragma unroll
            for (int i = 0; i < 16; i++) oacc[i] += wd * accL[i];
        }
        __syncthreads();   // sb overwritten next dir
    }

    // transpose via sb (reuse as outT[64][65], conflict-free stride)
#pragma unroll
    for (int i = 0; i < 16; i++)
        sb[oc * 65 + grp * 16 + i] = oacc[i];
    __syncthreads();
    for (int o = tid; o < 4096; o += 256) {
        int c = o >> 6, j = o & 63;
        out[c * CS + p0 + j] = sb[c * 65 + j];
    }
}

// ====================== SMALL PATH (v5, proven) ============================

__global__ void prep_kernel(const float* __restrict__ ip,
                            const float* __restrict__ op,
                            float* __restrict__ ws)
{
    float* ipT = ws + IPT_OFF;
    float* opT = ws + OPT_OFF;
    int i = blockIdx.x * 256 + threadIdx.x;
    if (i < 3 * 256 * 64) {
        int dir = i / 16384, r = i % 16384, j = r / 64, c = r % 64;
        ipT[dir * 16384 + c * 256 + j] = ip[i];
    } else {
        int k = i - 3 * 256 * 64;
        if (k < 3 * 64 * 128) {
            int dir = k / 8192, r = k % 8192, c = r / 128, dch = r % 128;
            opT[dir * 8192 + dch * 64 + c] = op[k];
        }
    }
}

template<int DIR>
__global__ __launch_bounds__(256, 4)
void k1_lnproj(const float* __restrict__ x,
               const float* __restrict__ ln_g,
               const float* __restrict__ ln_b,
               float* __restrict__ ws)
{
    __shared__ float Xs[64 * 64];
    const float* ipT = ws + IPT_OFF + DIR * 16384;
    float* tb = ws;
    const int tid = threadIdx.x;
    const int p0 = blockIdx.x * 64;
    {
        const int c0 = tid >> 6, j = tid & 63;
#pragma unroll
        for (int cc = 0; cc < 16; cc++) {
            int c = cc * 4 + c0;
            Xs[c * 64 + j] = x[c * CS + p0 + j];
        }
    }
    __syncthreads();
    if (tid < 64) {
        float s1 = 0.f, s2 = 0.f;
#pragma unroll
        for (int c = 0; c < 64; c++) {
            float v = Xs[c * 64 + tid];
            s1 += v; s2 += v * v;
        }
        float m  = s1 * (1.f / 64.f);
        float rs = rsqrtf(s2 * (1.f / 64.f) - m * m + 1e-5f);
#pragma unroll
        for (int c = 0; c < 64; c++) {
            Xs[c * 64 + tid] = (Xs[c * 64 + tid] - m) * rs * ln_g[DIR * 64 + c]
                               + ln_b[DIR * 64 + c];
        }
    }
    __syncthreads();
    const int ch = tid & 127, half = tid >> 7;
    float wgt[64];
#pragma unroll
    for (int c = 0; c < 64; c++) wgt[c] = ipT[c * 256 + ch];
#pragma unroll
    for (int gg = 0; gg < 2; gg++) {
        int g = half * 2 + gg;
        float acc[16];
#pragma unroll
        for (int i = 0; i < 16; i++) acc[i] = 0.f;
#pragma unroll 8
        for (int c = 0; c < 64; c++) {
            const float4* xr = (const float4*)&Xs[c * 64 + g * 16];
            float4 x0 = xr[0], x1 = xr[1], x2 = xr[2], x3 = xr[3];
            float wv = wgt[c];
            acc[0]  += x0.x * wv; acc[1]  += x0.y * wv;
            acc[2]  += x0.z * wv; acc[3]  += x0.w * wv;
            acc[4]  += x1.x * wv; acc[5]  += x1.y * wv;
            acc[6]  += x1.z * wv; acc[7]  += x1.w * wv;
            acc[8]  += x2.x * wv; acc[9]  += x2.y * wv;
            acc[10] += x2.z * wv; acc[11] += x2.w * wv;
            acc[12] += x3.x * wv; acc[13] += x3.y * wv;
            acc[14] += x3.z * wv; acc[15] += x3.w * wv;
        }
#pragma unroll
        for (int i = 0; i < 16; i++)
            tb[(size_t)(p0 + g * 16 + i) * 128 + ch] = acc[i];
    }
}

template<int DIR>
__global__ __launch_bounds__(128, 2)
void k2_scan(const float* __restrict__ conv_w,
             const float* __restrict__ conv_b,
             const float* __restrict__ x_proj,
             const float* __restrict__ dt_w,
             const float* __restrict__ dt_b,
             const float* __restrict__ A_log,
             const float* __restrict__ D_ssm,
             float* __restrict__ ws)
{
    __shared__ float u_s[48 * 128];
    __shared__ float xd_s[48 * 36];
    float* tb = ws;
    const int tid = threadIdx.x;
    const int s = blockIdx.x;
    int base, TS;
    if (DIR == 0)      { base = s;                               TS = 2304; }
    else if (DIR == 1) { base = (s / 48) * 2304 + (s % 48);      TS = 48;   }
    else               { base = (s / 48) * 2304 + (s % 48) * 48; TS = 1;    }
    {
        const int d = tid;
        float xin[48];
#pragma unroll
        for (int t = 0; t < 48; t++)
            xin[t] = tb[(size_t)(base + t * TS) * 128 + d];
        float4 cw = *(const float4*)(conv_w + DIR * 512 + d * 4);
        float cb  = conv_b[DIR * 128 + d];
#pragma unroll
        for (int t = 0; t < 48; t++) {
            float a0 = (t >= 3) ? xin[t-3] : 0.f;
            float a1 = (t >= 2) ? xin[t-2] : 0.f;
            float a2 = (t >= 1) ? xin[t-1] : 0.f;
            float v = cw.x * a0 + cw.y * a1 + cw.z * a2 + cw.w * xin[t] + cb;
            u_s[t * 128 + (((((d >> 2) ^ (t & 7))) << 2) | (d & 3))] = fast_silu(v);
        }
    }
    __syncthreads();
    {
        const int t  = tid & 63;
        const int wv = __builtin_amdgcn_readfirstlane(tid >> 6);
        const int tr = (t < 48) ? t : 47;
        const int sw = tr & 7;
        float acc[18];
#pragma unroll
        for (int j = 0; j < 18; j++) acc[j] = 0.f;
        const float* xpw = x_proj + DIR * 36 * 128 + (wv * 18) * 128;
        const float4* urow = (const float4*)&u_s[tr * 128];
#pragma unroll
        for (int qc = 0; qc < 4; qc++) {
            float4 u4[8];
#pragma unroll
            for (int q = 0; q < 8; q++) u4[q] = urow[qc * 8 + (q ^ sw)];
#pragma unroll
            for (int j = 0; j < 18; j++) {
                const float4* wr = (const float4*)(xpw + j * 128 + qc * 32);
                float a0 = 0.f, a1 = 0.f, a2 = 0.f, a3 = 0.f;
#pragma unroll
                for (int q = 0; q < 8; q++) {
                    float4 w4 = wr[q];
                    a0 += u4[q].x * w4.x; a1 += u4[q].y * w4.y;
                    a2 += u4[q].z * w4.z; a3 += u4[q].w * w4.w;
                }
                acc[j] += (a0 + a1) + (a2 + a3);
            }
        }
        if (t < 48) {
#pragma unroll
            for (int j = 0; j < 18; j++) xd_s[t * 36 + wv * 18 + j] = acc[j];
        }
    }
    __syncthreads();
    {
        const int d = tid;
        float A[16];
        {
            const float4* al = (const float4*)(A_log + DIR * 2048 + d * 16);
#pragma unroll
            for (int q = 0; q < 4; q++) {
                float4 v = al[q];
                A[4*q+0] = -__expf(v.x); A[4*q+1] = -__expf(v.y);
                A[4*q+2] = -__expf(v.z); A[4*q+3] = -__expf(v.w);
            }
        }
        float4 dtw = *(const float4*)(dt_w + DIR * 512 + d * 4);
        float dtbv = dt_b[DIR * 128 + d];
        float dsv  = D_ssm[DIR * 128 + d];
        float h[16];
#pragma unroll
        for (int n = 0; n < 16; n++) h[n] = 0.f;
        const int dsw_hi = d >> 2, dlo = d & 3;
        for (int tt = 0; tt < 48; tt++) {
            const float4* xr4 = (const float4*)&xd_s[tt * 36];
            float4 R0 = xr4[0];
            float uu = u_s[tt * 128 + (((dsw_hi ^ (tt & 7)) << 2) | dlo)];
            float dl = dtbv + dtw.x*R0.x + dtw.y*R0.y + dtw.z*R0.z + dtw.w*R0.w;
            float delta = softplus_f(dl);
            float du = delta * uu;
            float4 B0 = xr4[1], B1 = xr4[2], B2 = xr4[3], B3 = xr4[4];
            float4 C0 = xr4[5], C1 = xr4[6], C2 = xr4[7], C3 = xr4[8];
            float y0 = 0.f, y1 = 0.f, y2 = 0.f, y3 = 0.f;
#define HN(n, Bc, Cc, ya) { float e = __expf(delta * A[n]); \
            h[n] = e * h[n] + du * (Bc); ya += h[n] * (Cc); }
            HN(0,  B0.x, C0.x, y0) HN(1,  B0.y, C0.y, y1)
            HN(2,  B0.z, C0.z, y2) HN(3,  B0.w, C0.w, y3)
            HN(4,  B1.x, C1.x, y0) HN(5,  B1.y, C1.y, y1)
            HN(6,  B1.z, C1.z, y2) HN(7,  B1.w, C1.w, y3)
            HN(8,  B2.x, C2.x, y0) HN(9,  B2.y, C2.y, y1)
            HN(10, B2.z, C2.z, y2) HN(11, B2.w, C2.w, y3)
            HN(12, B3.x, C3.x, y0) HN(13, B3.y, C3.y, y1)
            HN(14, B3.z, C3.z, y2) HN(15, B3.w, C3.w, y3)
#undef HN
            tb[(size_t)(base + tt * TS) * 128 + d] =
                ((y0 + y1) + (y2 + y3)) + uu * dsv;
        }
    }
}

template<int DIR, bool FIRST>
__global__ __launch_bounds__(128, 4)
void k3_outproj(const float* __restrict__ x,
                const float* __restrict__ ln_g,
                const float* __restrict__ ln_b,
                const float* __restrict__ alpha,
                float* __restrict__ ws,
                float* __restrict__ out)
{
    __shared__ float sb[48 * 132];
    __shared__ float xs[64 * 52];
    float* tb = ws;
    const float* ipT = ws + IPT_OFF + DIR * 16384;
    const float* opT = ws + OPT_OFF + DIR * 8192;
    const int tid = threadIdx.x;
    const int b = blockIdx.x;
    const int d_sp = b / 48;
    const int h = b - d_sp * 48;
    const int obase = d_sp * 2304 + h * 48;
    float a0 = alpha[0], a1 = alpha[1], a2 = alpha[2];
    float mx = fmaxf(a0, fmaxf(a1, a2));
    float e0 = __expf(a0 - mx), e1 = __expf(a1 - mx), e2 = __expf(a2 - mx);
    float wdir = ((DIR == 0) ? e0 : (DIR == 1) ? e1 : e2) / (e0 + e1 + e2);
    for (int o = tid; o < 64 * 48; o += 128) {
        int c = o / 48, w = o - c * 48;
        xs[c * 52 + w] = x[c * CS + obase + w];
    }
    __syncthreads();
    if (tid < 48) {
        const int w = tid;
        float s1 = 0.f, s2 = 0.f;
#pragma unroll
        for (int c = 0; c < 64; c++) {
            float v = xs[c * 52 + w];
            s1 += v; s2 += v * v;
        }
        float m  = s1 * (1.f / 64.f);
        float rs = rsqrtf(s2 * (1.f / 64.f) - m * m + 1e-5f);
#pragma unroll
        for (int c = 0; c < 64; c++) {
            xs[c * 52 + w] = (xs[c * 52 + w] - m) * rs * ln_g[DIR * 64 + c]
                             + ln_b[DIR * 64 + c];
        }
    }
    __syncthreads();
    {
        const int d = tid;
        float wgt2[64];
#pragma unroll
        for (int c = 0; c < 64; c++) wgt2[c] = ipT[c * 256 + 128 + d];
#pragma unroll
        for (int wb = 0; wb < 4; wb++) {
            float acc[12];
#pragma unroll
            for (int i = 0; i < 12; i++) acc[i] = 0.f;
#pragma unroll 8
            for (int c = 0; c < 64; c++) {
                const float4* xr = (const float4*)&xs[c * 52 + wb * 12];
                float4 v0 = xr[0], v1 = xr[1], v2 = xr[2];
                float wv = wgt2[c];
                acc[0] += v0.x * wv; acc[1] += v0.y * wv;
                acc[2] += v0.z * wv; acc[3] += v0.w * wv;
                acc[4] += v1.x * wv; acc[5] += v1.y * wv;
                acc[6] += v1.z * wv; acc[7] += v1.w * wv;
                acc[8] += v2.x * wv; acc[9] += v2.y * wv;
                acc[10] += v2.z * wv; acc[11] += v2.w * wv;
            }
#pragma unroll
            for (int i = 0; i < 12; i++) {
                int w = wb * 12 + i;
                float zv = tb[(size_t)(obase + w) * 128 + d];
                sb[w * 132 + d] = zv * fast_silu(acc[i]);
            }
        }
    }
    __syncthreads();
    const int cp = tid & 31;
    const int wg = tid >> 5;
    float acc0[12], acc1[12];
#pragma unroll
    for (int i = 0; i < 12; i++) { acc0[i] = 0.f; acc1[i] = 0.f; }
#pragma unroll 2
    for (int dc = 0; dc < 32; dc++) {
        float w0[4], w1[4];
#pragma unroll
        for (int i = 0; i < 4; i++) {
            w0[i] = opT[(dc * 4 + i) * 64 + cp];
            w1[i] = opT[(dc * 4 + i) * 64 + cp + 32];
        }
#pragma unroll
        for (int i = 0; i < 12; i++) {
            int w = wg * 12 + i;
            float4 z4 = *(const float4*)&sb[w * 132 + dc * 4];
            acc0[i] += z4.x * w0[0] + z4.y * w0[1] + z4.z * w0[2] + z4.w * w0[3];
            acc1[i] += z4.x * w1[0] + z4.y * w1[1] + z4.z * w1[2] + z4.w * w1[3];
        }
    }
    __syncthreads();
#pragma unroll
    for (int i = 0; i < 12; i++) {
        int w = wg * 12 + i;
        sb[cp * 49 + w]        = acc0[i];
        sb[(cp + 32) * 49 + w] = acc1[i];
    }
    __syncthreads();
    for (int o = tid; o < 3072; o += 128) {
        int c = o / 48, w = o - c * 48;
        int addr = c * CS + obase + w;
        float val = wdir * sb[c * 49 + w];
        if (!FIRST) val += out[addr];
        out[addr] = val;
    }
}

// ------------------------------------------------------------- launch -----
extern "C" void kernel_launch(void* const* d_in, const int* in_sizes, int n_in,
                              void* d_out, int out_size, void* d_ws, size_t ws_size,
                              hipStream_t stream) {
    const float* x        = (const float*)d_in[0];
    const float* in_proj  = (const float*)d_in[1];
    const float* conv_w   = (const float*)d_in[2];
    const float* conv_b   = (const float*)d_in[3];
    const float* x_proj   = (const float*)d_in[4];
    const float* dt_w     = (const float*)d_in[5];
    const float* dt_b     = (const float*)d_in[6];
    const float* A_log    = (const float*)d_in[7];
    const float* D_ssm    = (const float*)d_in[8];
    const float* out_proj = (const float*)d_in[9];
    const float* ln_g     = (const float*)d_in[10];
    const float* ln_b     = (const float*)d_in[11];
    const float* alpha    = (const float*)d_in[12];
    float* out = (float*)d_out;
    float* ws  = (float*)d_ws;

    if (ws_size >= (size_t)WS_BIG * 4) {
        prep_big<<<288, 256, 0, stream>>>(in_proj, out_proj, ln_g, ws);
        prep_s12<<<3, 256, 0, stream>>>(in_proj, ln_g, ln_b, ws);
        k1_all<<<1728, 256, 0, stream>>>(x, ws);
        k2_all<<<6912, 128, 0, stream>>>(conv_w, conv_b, x_proj, dt_w, dt_b,
                                         A_log, D_ssm, ws);
        k3_all<<<1728, 256, 0, stream>>>(x, alpha, ws, out);
    } else {
        prep_kernel<<<288, 256, 0, stream>>>(in_proj, out_proj, ws);

        k1_lnproj<0><<<1728, 256, 0, stream>>>(x, ln_g, ln_b, ws);
        k2_scan<0><<<2304, 128, 0, stream>>>(conv_w, conv_b, x_proj, dt_w, dt_b, A_log, D_ssm, ws);
        k3_outproj<0, true ><<<2304, 128, 0, stream>>>(x, ln_g, ln_b, alpha, ws, out);

        k1_lnproj<1><<<1728, 256, 0, stream>>>(x, ln_g, ln_b, ws);
        k2_scan<1><<<2304, 128, 0, stream>>>(conv_w, conv_b, x_proj, dt_w, dt_b, A_log, D_ssm, ws);
        k3_outproj<1, false><<<2304, 128, 0, stream>>>(x, ln_g, ln_b, alpha, ws, out);

        k1_lnproj<2><<<1728, 256, 0, stream>>>(x, ln_g, ln_b, ws);
        k2_scan<2><<<2304, 128, 0, stream>>>(conv_w, conv_b, x_proj, dt_w, dt_b, A_log, D_ssm, ws);
        k3_outproj<2, false><<<2304, 128, 0, stream>>>(x, ln_g, ln_b, alpha, ws, out);
    }
}